// Round 1
// baseline (711.235 us; speedup 1.0000x reference)
//
#include <hip/hip_runtime.h>
#include <hip/hip_bf16.h>

// DimeNet InteractionBlock for MI355X (gfx950).
// Sizes fixed by the problem:
#define HH   128
#define NEDGE 50000
#define NTRI 200000

typedef __attribute__((ext_vector_type(8))) short short8;   // 8 bf16 (4 VGPRs) — MFMA A/B frag
typedef __attribute__((ext_vector_type(4))) short short4v;
typedef __attribute__((ext_vector_type(4))) float f32x4;    // MFMA C/D frag

__device__ __forceinline__ float silu_f(float v) { return v / (1.0f + __expf(-v)); }

// f32 -> bf16 bits, round-to-nearest-even
__device__ __forceinline__ short f2bf(float f) {
    unsigned u = __float_as_uint(f);
    unsigned r = (u + 0x7FFFu + ((u >> 16) & 1u)) >> 16;
    return (short)r;
}
__device__ __forceinline__ float bf2f(short s) {
    return __uint_as_float(((unsigned)(unsigned short)s) << 16);
}

// ---------- prep kernels ----------

// straight f32 -> bf16 convert (n4 = count of float4 groups)
__global__ void cvt_kernel(const float* __restrict__ src, short* __restrict__ dst, int n4) {
    int i = blockIdx.x * 256 + threadIdx.x;
    if (i < n4) {
        float4 v = ((const float4*)src)[i];
        short4v o;
        o[0] = f2bf(v.x); o[1] = f2bf(v.y); o[2] = f2bf(v.z); o[3] = f2bf(v.w);
        ((short4v*)dst)[i] = o;
    }
}

// 10x 128x128 transpose+convert: dst[n*128+k] = bf16(src[k*128+n])
struct TP { const float* s[10]; short* d[10]; };
__global__ void t128_all(TP p) {
    const float* __restrict__ src = p.s[blockIdx.y];
    short* __restrict__ dst = p.d[blockIdx.y];
    int i = blockIdx.x * 256 + threadIdx.x;    // grid.x = 64 -> 16384 exactly
    int k = i >> 7, n = i & 127;
    dst[n * 128 + k] = f2bf(src[i]);
}

// sbf_h = sbf @ W_sbf : [T,42]@[42,8] -> f32 [T,8]
__global__ void sbfh_kernel(const float* __restrict__ sbf, const float* __restrict__ Wsbf,
                            float* __restrict__ out) {
    int i = blockIdx.x * 256 + threadIdx.x;
    if (i >= NTRI * 8) return;
    int row = i >> 3, j = i & 7;
    const float* sr = sbf + (size_t)row * 42;
    float acc = 0.f;
    #pragma unroll
    for (int s = 0; s < 42; ++s) acc += sr[s] * Wsbf[s * 8 + j];
    out[i] = acc;
}

// h = xji + agg (f32), hb = bf16(h)
__global__ void h0_kernel(const float* __restrict__ xji, const float* __restrict__ agg,
                          float* __restrict__ h, short* __restrict__ hb) {
    int i = blockIdx.x * 256 + threadIdx.x;
    if (i < NEDGE * 128 / 4) {
        float4 a = ((const float4*)xji)[i];
        float4 b = ((const float4*)agg)[i];
        float4 v; v.x = a.x + b.x; v.y = a.y + b.y; v.z = a.z + b.z; v.w = a.w + b.w;
        ((float4*)h)[i] = v;
        short4v o;
        o[0] = f2bf(v.x); o[1] = f2bf(v.y); o[2] = f2bf(v.z); o[3] = f2bf(v.w);
        ((short4v*)hb)[i] = o;
    }
}

// ---------- generic [M,128] @ [128,128] bf16 MFMA GEMM with fused epilogues ----------
// A bf16 row-major [M,128]; Wt bf16 pre-transposed [n][k] (Wt[n*128+k] = W[k][n]).
// Block = 256 thr = 4 waves; wave w owns rows blockIdx*64 + w*16 .. +16.
// MODE 0: of32 = silu(acc+bias)                          (x_ji)
// MODE 1: ob16 = bf16(silu(acc+bias) * (rbf@W_rbf))      (x_kj; aux0=rbf, aux1=W_rbf)
// MODE 2: ob16 = bf16(silu(acc+bias))                    (t of residual MLP)
// MODE 3: h += silu(acc+bias); ob16 = bf16(h)            (residual second half; hbuf=h)
// MODE 4: h = silu(acc+bias) + aux0; ob16 = bf16(h)      (lin + x residual; aux0=x f32)
// MODE 5: of32 = silu(acc+bias)                          (final out)
template<int MODE>
__global__ __launch_bounds__(256) void gemm128(
    const short* __restrict__ A, const short* __restrict__ Wt,
    const float* __restrict__ bias, int M,
    float* __restrict__ of32, short* __restrict__ ob16,
    const float* __restrict__ aux0, const float* __restrict__ aux1,
    float* __restrict__ hbuf)
{
    int wave = threadIdx.x >> 6, lane = threadIdx.x & 63;
    int g = lane >> 4, ln = lane & 15;
    int rowBase = blockIdx.x * 64 + wave * 16;

    int arow = rowBase + ln; if (arow > M - 1) arow = M - 1;
    const short8* Ar = (const short8*)(A + (size_t)arow * 128);
    short8 af[4];
    #pragma unroll
    for (int kc = 0; kc < 4; ++kc) af[kc] = Ar[kc * 4 + g];   // k = kc*32 + g*8 + e

    f32x4 acc[8];
    #pragma unroll
    for (int nt = 0; nt < 8; ++nt) acc[nt] = (f32x4){0.f, 0.f, 0.f, 0.f};

    #pragma unroll
    for (int kc = 0; kc < 4; ++kc) {
        #pragma unroll
        for (int nt = 0; nt < 8; ++nt) {
            short8 b = *(const short8*)(Wt + (nt * 16 + ln) * 128 + kc * 32 + g * 8);
            acc[nt] = __builtin_amdgcn_mfma_f32_16x16x32_bf16(af[kc], b, acc[nt], 0, 0, 0);
        }
    }

    #pragma unroll
    for (int nt = 0; nt < 8; ++nt) {
        int col = nt * 16 + ln;
        float bv = bias[col];
        #pragma unroll
        for (int r = 0; r < 4; ++r) {
            int row = rowBase + g * 4 + r;   // C/D: row=(lane>>4)*4+reg, col=lane&15
            if (row < M) {
                size_t o = (size_t)row * 128 + col;
                float v = acc[nt][r] + bv;
                if constexpr (MODE == 0) {
                    of32[o] = silu_f(v);
                } else if constexpr (MODE == 1) {
                    float rb = 0.f;
                    const float* rr = aux0 + (size_t)row * 6;
                    #pragma unroll
                    for (int q = 0; q < 6; ++q) rb += rr[q] * aux1[q * 128 + col];
                    ob16[o] = f2bf(silu_f(v) * rb);
                } else if constexpr (MODE == 2) {
                    ob16[o] = f2bf(silu_f(v));
                } else if constexpr (MODE == 3) {
                    float nv = hbuf[o] + silu_f(v);
                    hbuf[o] = nv; ob16[o] = f2bf(nv);
                } else if constexpr (MODE == 4) {
                    float nv = silu_f(v) + aux0[o];
                    hbuf[o] = nv; ob16[o] = f2bf(nv);
                } else {
                    of32[o] = silu_f(v);
                }
            }
        }
    }
}

// ---------- bilinear: msg = (sbf_h ⊗ xg) @ WbT, atomically scattered to agg[idx_ji] ----------
// A2[w, j*128+l] = sbf_h[w,j]*x_kj[idx_kj[w], l]; WbT[i*1024 + j*128 + l] = Wbil[i][j][l] (native flat).
// Block = 256 thr = 4 waves; BM=128 rows/block; wave w owns rows w*32..w*32+32 (two 16-row tiles).
__global__ __launch_bounds__(256) void bilinear_kernel(
    const short* __restrict__ xkj, const float* __restrict__ sbfh,
    const short* __restrict__ WbT, const int* __restrict__ idx_kj,
    const int* __restrict__ idx_ji, float* __restrict__ agg)
{
    __shared__ __align__(16) short xg[128 * 128];  // gathered x_kj rows, XOR-swizzled
    __shared__ __align__(16) float sb[128 * 8];
    __shared__ int ij[128];
    __shared__ int ik[128];

    int tid = threadIdx.x;
    int gbase = blockIdx.x * 128;

    for (int r = tid; r < 128; r += 256) {
        int t = gbase + r; if (t > NTRI - 1) t = NTRI - 1;
        ij[r] = idx_ji[t];
        ik[r] = idx_kj[t];
    }
    {   // sbf_h tile: 128 rows x 2 float4 = 256 units (one per thread)
        int r = tid >> 1, part = tid & 1;
        int t = gbase + r; if (t > NTRI - 1) t = NTRI - 1;
        *(float4*)&sb[r * 8 + part * 4] = *(const float4*)(sbfh + (size_t)t * 8 + part * 4);
    }
    __syncthreads();

    // gather xg: 128 rows x 16 short8 units; swizzle byte ^= (row&7)<<4 (T2 fix for
    // the 256B-stride ds_read_b128 bank conflict)
    #pragma unroll
    for (int it = 0; it < 8; ++it) {
        int u = tid + it * 256;
        int r = u >> 4, c8 = u & 15;
        unsigned bo = (unsigned)(r * 256 + c8 * 16) ^ (unsigned)((r & 7) << 4);
        *(short8*)((char*)xg + bo) = *(const short8*)(xkj + (size_t)ik[r] * 128 + c8 * 8);
    }
    __syncthreads();

    int wave = tid >> 6, lane = tid & 63, g = lane >> 4, ln = lane & 15;
    int r0 = wave * 32 + ln, r1 = r0 + 16;

    float s0[8], s1[8];
    #pragma unroll
    for (int j = 0; j < 8; ++j) { s0[j] = sb[r0 * 8 + j]; s1[j] = sb[r1 * 8 + j]; }

    f32x4 acc[2][8];
    #pragma unroll
    for (int m = 0; m < 2; ++m)
        #pragma unroll
        for (int nt = 0; nt < 8; ++nt) acc[m][nt] = (f32x4){0.f, 0.f, 0.f, 0.f};

    #pragma unroll
    for (int kq = 0; kq < 4; ++kq) {          // position within the 128-wide l axis
        unsigned bo0 = (unsigned)(r0 * 256 + kq * 64 + g * 16) ^ (unsigned)((r0 & 7) << 4);
        unsigned bo1 = (unsigned)(r1 * 256 + kq * 64 + g * 16) ^ (unsigned)((r1 & 7) << 4);
        short8 xv0 = *(short8*)((char*)xg + bo0);
        short8 xv1 = *(short8*)((char*)xg + bo1);
        float xf0[8], xf1[8];
        #pragma unroll
        for (int e = 0; e < 8; ++e) { xf0[e] = bf2f(xv0[e]); xf1[e] = bf2f(xv1[e]); }
        #pragma unroll
        for (int j = 0; j < 8; ++j) {         // j-block of K (k = j*128 + kq*32 + g*8 + e)
            short8 a0, a1;
            #pragma unroll
            for (int e = 0; e < 8; ++e) {
                a0[e] = f2bf(s0[j] * xf0[e]);
                a1[e] = f2bf(s1[j] * xf1[e]);
            }
            int kcol = j * 128 + kq * 32 + g * 8;
            #pragma unroll
            for (int nt = 0; nt < 8; ++nt) {
                short8 b = *(const short8*)(WbT + (size_t)(nt * 16 + ln) * 1024 + kcol);
                acc[0][nt] = __builtin_amdgcn_mfma_f32_16x16x32_bf16(a0, b, acc[0][nt], 0, 0, 0);
                acc[1][nt] = __builtin_amdgcn_mfma_f32_16x16x32_bf16(a1, b, acc[1][nt], 0, 0, 0);
            }
        }
    }

    #pragma unroll
    for (int m = 0; m < 2; ++m)
        #pragma unroll
        for (int nt = 0; nt < 8; ++nt)
            #pragma unroll
            for (int r = 0; r < 4; ++r) {
                int lrow = wave * 32 + m * 16 + g * 4 + r;
                if (gbase + lrow < NTRI) {
                    atomicAdd(agg + (size_t)ij[lrow] * 128 + nt * 16 + ln, acc[m][nt][r]);
                }
            }
}

// ---------- launch ----------
extern "C" void kernel_launch(void* const* d_in, const int* in_sizes, int n_in,
                              void* d_out, int out_size, void* d_ws, size_t ws_size,
                              hipStream_t stream) {
    const float* x      = (const float*)d_in[0];
    const float* rbf    = (const float*)d_in[1];
    const float* sbf    = (const float*)d_in[2];
    const int*   idx_kj = (const int*)d_in[3];
    const int*   idx_ji = (const int*)d_in[4];
    const float* W_rbf  = (const float*)d_in[5];
    const float* W_sbf  = (const float*)d_in[6];
    const float* Wkj    = (const float*)d_in[7];
    const float* bkj    = (const float*)d_in[8];
    const float* Wji    = (const float*)d_in[9];
    const float* bji    = (const float*)d_in[10];
    const float* Wbil   = (const float*)d_in[11];
    const float* bW1    = (const float*)d_in[12];
    const float* bb1    = (const float*)d_in[13];
    const float* bW2    = (const float*)d_in[14];
    const float* bb2    = (const float*)d_in[15];
    const float* Wlin   = (const float*)d_in[16];
    const float* blin   = (const float*)d_in[17];
    const float* aW1    = (const float*)d_in[18];
    const float* ab1    = (const float*)d_in[19];
    const float* aW2    = (const float*)d_in[20];
    const float* ab2    = (const float*)d_in[21];
    const float* Wout   = (const float*)d_in[22];
    const float* bout   = (const float*)d_in[23];
    float* out = (float*)d_out;

    char* ws = (char*)d_ws;
    size_t off = 0;
    auto alloc = [&](size_t bytes) { char* p = ws + off; off += bytes; return p; };
    short* xb   = (short*)alloc((size_t)NEDGE * 128 * 2);
    short* xkj  = (short*)alloc((size_t)NEDGE * 128 * 2);
    short* hb   = (short*)alloc((size_t)NEDGE * 128 * 2);
    short* tb   = (short*)alloc((size_t)NEDGE * 128 * 2);
    float* sbfh = (float*)alloc((size_t)NTRI * 8 * 4);
    float* xji  = (float*)alloc((size_t)NEDGE * 128 * 4);
    float* agg  = (float*)alloc((size_t)NEDGE * 128 * 4);
    float* h    = (float*)alloc((size_t)NEDGE * 128 * 4);
    short* WbT  = (short*)alloc((size_t)131072 * 2);
    short* Wt[10];
    for (int i = 0; i < 10; ++i) Wt[i] = (short*)alloc((size_t)16384 * 2);
    (void)ws_size; (void)n_in; (void)in_sizes; (void)out_size;

    hipMemsetAsync(agg, 0, (size_t)NEDGE * 128 * 4, stream);

    cvt_kernel<<<dim3((NEDGE * 128 / 4 + 255) / 256), 256, 0, stream>>>(x, xb, NEDGE * 128 / 4);
    cvt_kernel<<<dim3((131072 / 4 + 255) / 256), 256, 0, stream>>>(Wbil, WbT, 131072 / 4);

    TP tp;
    const float* srcs[10] = {Wkj, Wji, bW1, bW2, Wlin, aW1, aW1 + 16384, aW2, aW2 + 16384, Wout};
    for (int i = 0; i < 10; ++i) { tp.s[i] = srcs[i]; tp.d[i] = Wt[i]; }
    t128_all<<<dim3(64, 10), 256, 0, stream>>>(tp);

    sbfh_kernel<<<dim3((NTRI * 8 + 255) / 256), 256, 0, stream>>>(sbf, W_sbf, sbfh);

    int gE = (NEDGE + 63) / 64;
    // x_ji = silu(x @ Wji + bji) -> f32
    gemm128<0><<<gE, 256, 0, stream>>>(xb, Wt[1], bji, NEDGE, xji, nullptr, nullptr, nullptr, nullptr);
    // x_kj = silu(x @ Wkj + bkj) * (rbf @ W_rbf) -> bf16
    gemm128<1><<<gE, 256, 0, stream>>>(xb, Wt[0], bkj, NEDGE, nullptr, xkj, rbf, W_rbf, nullptr);

    bilinear_kernel<<<dim3((NTRI + 127) / 128), 256, 0, stream>>>(xkj, sbfh, WbT, idx_kj, idx_ji, agg);

    h0_kernel<<<dim3((NEDGE * 128 / 4 + 255) / 256), 256, 0, stream>>>(xji, agg, h, hb);

    // before residual block
    gemm128<2><<<gE, 256, 0, stream>>>(hb, Wt[2], bb1, NEDGE, nullptr, tb, nullptr, nullptr, nullptr);
    gemm128<3><<<gE, 256, 0, stream>>>(tb, Wt[3], bb2, NEDGE, nullptr, hb, nullptr, nullptr, h);
    // h = silu(h @ Wlin + blin) + x
    gemm128<4><<<gE, 256, 0, stream>>>(hb, Wt[4], blin, NEDGE, nullptr, hb, x, nullptr, h);
    // after residual block 0
    gemm128<2><<<gE, 256, 0, stream>>>(hb, Wt[5], ab1, NEDGE, nullptr, tb, nullptr, nullptr, nullptr);
    gemm128<3><<<gE, 256, 0, stream>>>(tb, Wt[7], ab2, NEDGE, nullptr, hb, nullptr, nullptr, h);
    // after residual block 1
    gemm128<2><<<gE, 256, 0, stream>>>(hb, Wt[6], ab1 + 128, NEDGE, nullptr, tb, nullptr, nullptr, nullptr);
    gemm128<3><<<gE, 256, 0, stream>>>(tb, Wt[8], ab2 + 128, NEDGE, nullptr, hb, nullptr, nullptr, h);
    // out = silu(h @ Wout + bout)
    gemm128<5><<<gE, 256, 0, stream>>>(hb, Wt[9], bout, NEDGE, out, nullptr, nullptr, nullptr, nullptr);
}

// Round 2
// 668.749 us; speedup vs baseline: 1.0635x; 1.0635x over previous
//
#include <hip/hip_runtime.h>
#include <hip/hip_bf16.h>

// DimeNet InteractionBlock for MI355X (gfx950).
#define HH   128
#define NEDGE 50000
#define NTRI 200000

typedef __attribute__((ext_vector_type(8))) short short8;   // 8 bf16 (4 VGPRs) — MFMA A/B frag
typedef __attribute__((ext_vector_type(4))) short short4v;
typedef __attribute__((ext_vector_type(4))) float f32x4;    // MFMA C/D frag

__device__ __forceinline__ float silu_f(float v) { return v / (1.0f + __expf(-v)); }

// f32 -> bf16 bits, round-to-nearest-even
__device__ __forceinline__ short f2bf(float f) {
    unsigned u = __float_as_uint(f);
    unsigned r = (u + 0x7FFFu + ((u >> 16) & 1u)) >> 16;
    return (short)r;
}
__device__ __forceinline__ float bf2f(short s) {
    return __uint_as_float(((unsigned)(unsigned short)s) << 16);
}

// ---------- prep kernels ----------

__global__ void cvt_kernel(const float* __restrict__ src, short* __restrict__ dst, int n4) {
    int i = blockIdx.x * 256 + threadIdx.x;
    if (i < n4) {
        float4 v = ((const float4*)src)[i];
        short4v o;
        o[0] = f2bf(v.x); o[1] = f2bf(v.y); o[2] = f2bf(v.z); o[3] = f2bf(v.w);
        ((short4v*)dst)[i] = o;
    }
}

// 10x 128x128 transpose+convert: dst[n*128+k] = bf16(src[k*128+n])
struct TP { const float* s[10]; short* d[10]; };
__global__ void t128_all(TP p) {
    const float* __restrict__ src = p.s[blockIdx.y];
    short* __restrict__ dst = p.d[blockIdx.y];
    int i = blockIdx.x * 256 + threadIdx.x;    // grid.x = 64 -> 16384 exactly
    int k = i >> 7, n = i & 127;
    dst[n * 128 + k] = f2bf(src[i]);
}

// sbf_h = sbf @ W_sbf : [T,42]@[42,8] -> f32 [T,8]
__global__ void sbfh_kernel(const float* __restrict__ sbf, const float* __restrict__ Wsbf,
                            float* __restrict__ out) {
    int i = blockIdx.x * 256 + threadIdx.x;
    if (i >= NTRI * 8) return;
    int row = i >> 3, j = i & 7;
    const float* sr = sbf + (size_t)row * 42;
    float acc = 0.f;
    #pragma unroll
    for (int s = 0; s < 42; ++s) acc += sr[s] * Wsbf[s * 8 + j];
    out[i] = acc;
}

// ---------- CSR build for idx_ji ----------

__global__ void hist_kernel(const int* __restrict__ ji, int* __restrict__ counts) {
    int i = blockIdx.x * 256 + threadIdx.x;
    if (i < NTRI) atomicAdd(&counts[ji[i]], 1);
}

// per-block inclusive scan -> exclusive partials + block sums
__global__ void scan1_kernel(const int* __restrict__ counts, int* __restrict__ partial,
                             int* __restrict__ bsum) {
    __shared__ int tmp[256];
    int tid = threadIdx.x;
    int i = blockIdx.x * 256 + tid;
    int v = (i < NEDGE) ? counts[i] : 0;
    tmp[tid] = v; __syncthreads();
    #pragma unroll
    for (int o = 1; o < 256; o <<= 1) {
        int t = (tid >= o) ? tmp[tid - o] : 0;
        __syncthreads();
        tmp[tid] += t;
        __syncthreads();
    }
    if (i < NEDGE) partial[i] = tmp[tid] - v;      // exclusive within block
    if (tid == 255) bsum[blockIdx.x] = tmp[255];
}

// single-block exclusive scan of block sums (NB1 <= 256)
__global__ void scan2_kernel(int* __restrict__ bsum, int nb) {
    __shared__ int tmp[256];
    int tid = threadIdx.x;
    int v = (tid < nb) ? bsum[tid] : 0;
    tmp[tid] = v; __syncthreads();
    #pragma unroll
    for (int o = 1; o < 256; o <<= 1) {
        int t = (tid >= o) ? tmp[tid - o] : 0;
        __syncthreads();
        tmp[tid] += t;
        __syncthreads();
    }
    if (tid < nb) bsum[tid] = tmp[tid] - v;        // exclusive, in place
}

__global__ void scan3_kernel(const int* __restrict__ partial, const int* __restrict__ bsum,
                             int* __restrict__ rowptr, int* __restrict__ wcur) {
    int i = blockIdx.x * 256 + threadIdx.x;
    if (i < NEDGE) {
        int r = partial[i] + bsum[blockIdx.x];
        rowptr[i] = r;
        wcur[i] = r;
    }
}

__global__ void scatter_kernel(const int* __restrict__ ji, int* __restrict__ wcur,
                               int* __restrict__ perm) {
    int w = blockIdx.x * 256 + threadIdx.x;
    if (w < NTRI) {
        int p = atomicAdd(&wcur[ji[w]], 1);
        perm[p] = w;
    }
}

// ---------- y build: y[e, j*128+l] = sum_{w in CSR(e)} sbf_h[w,j] * x_kj[idx_kj[w], l] ----------
__global__ __launch_bounds__(128) void ybuild_kernel(
    const short* __restrict__ xkj, const float* __restrict__ sbfh,
    const int* __restrict__ idx_kj, const int* __restrict__ rowptr,
    const int* __restrict__ counts, const int* __restrict__ perm,
    short* __restrict__ y)
{
    int e = blockIdx.x;
    int i = threadIdx.x;                  // column l
    float acc[8];
    #pragma unroll
    for (int j = 0; j < 8; ++j) acc[j] = 0.f;

    int p0 = rowptr[e], n = counts[e];
    for (int t = 0; t < n; ++t) {
        int w = perm[p0 + t];
        w = __builtin_amdgcn_readfirstlane(w);          // uniform -> SGPR
        int kj = idx_kj[w];
        kj = __builtin_amdgcn_readfirstlane(kj);
        float xv = bf2f(xkj[(size_t)kj * 128 + i]);     // coalesced 256B row gather
        const float* s = sbfh + (size_t)w * 8;
        #pragma unroll
        for (int j = 0; j < 8; ++j) acc[j] += s[j] * xv;
    }
    #pragma unroll
    for (int j = 0; j < 8; ++j)
        y[(size_t)e * 1024 + j * 128 + i] = f2bf(acc[j]);
}

// ---------- y GEMM: h = x_ji + y @ WbT^T ; [E,1024]@[1024,128] ----------
// WbT[i*1024 + j*128 + l] = Wbil[i][j][l] (native flat layout, bf16).
__global__ __launch_bounds__(256) void ygemm_kernel(
    const short* __restrict__ y, const short* __restrict__ WbT,
    const float* __restrict__ xji, float* __restrict__ h, short* __restrict__ hb)
{
    int wave = threadIdx.x >> 6, lane = threadIdx.x & 63;
    int g = lane >> 4, ln = lane & 15;
    int rowBase = blockIdx.x * 64 + wave * 16;

    int arow = rowBase + ln; if (arow > NEDGE - 1) arow = NEDGE - 1;
    const short8* Ar = (const short8*)(y + (size_t)arow * 1024);

    f32x4 acc[8];
    #pragma unroll
    for (int nt = 0; nt < 8; ++nt) acc[nt] = (f32x4){0.f, 0.f, 0.f, 0.f};

    #pragma unroll 4
    for (int kc = 0; kc < 32; ++kc) {                  // k = kc*32 + g*8 + e
        short8 a = Ar[kc * 4 + g];
        #pragma unroll
        for (int nt = 0; nt < 8; ++nt) {
            short8 b = *(const short8*)(WbT + (size_t)(nt * 16 + ln) * 1024 + kc * 32 + g * 8);
            acc[nt] = __builtin_amdgcn_mfma_f32_16x16x32_bf16(a, b, acc[nt], 0, 0, 0);
        }
    }

    #pragma unroll
    for (int nt = 0; nt < 8; ++nt) {
        int col = nt * 16 + ln;
        #pragma unroll
        for (int r = 0; r < 4; ++r) {
            int row = rowBase + g * 4 + r;             // C/D: row=(lane>>4)*4+reg, col=lane&15
            if (row < NEDGE) {
                size_t o = (size_t)row * 128 + col;
                float v = acc[nt][r] + xji[o];
                h[o] = v;
                hb[o] = f2bf(v);
            }
        }
    }
}

// ---------- generic [M,128] @ [128,128] bf16 MFMA GEMM with fused epilogues ----------
// MODE 0: of32 = silu(acc+bias)                          (x_ji)
// MODE 1: ob16 = bf16(silu(acc+bias) * (rbf@W_rbf))      (x_kj; aux0=rbf, aux1=W_rbf)
// MODE 2: ob16 = bf16(silu(acc+bias))                    (t of residual MLP)
// MODE 3: h += silu(acc+bias); ob16 = bf16(h)            (residual second half; hbuf=h)
// MODE 4: h = silu(acc+bias) + aux0; ob16 = bf16(h)      (lin + x residual; aux0=x f32)
// MODE 5: of32 = silu(acc+bias)                          (final out)
template<int MODE>
__global__ __launch_bounds__(256) void gemm128(
    const short* __restrict__ A, const short* __restrict__ Wt,
    const float* __restrict__ bias, int M,
    float* __restrict__ of32, short* __restrict__ ob16,
    const float* __restrict__ aux0, const float* __restrict__ aux1,
    float* __restrict__ hbuf)
{
    int wave = threadIdx.x >> 6, lane = threadIdx.x & 63;
    int g = lane >> 4, ln = lane & 15;
    int rowBase = blockIdx.x * 64 + wave * 16;

    int arow = rowBase + ln; if (arow > M - 1) arow = M - 1;
    const short8* Ar = (const short8*)(A + (size_t)arow * 128);
    short8 af[4];
    #pragma unroll
    for (int kc = 0; kc < 4; ++kc) af[kc] = Ar[kc * 4 + g];   // k = kc*32 + g*8 + e

    f32x4 acc[8];
    #pragma unroll
    for (int nt = 0; nt < 8; ++nt) acc[nt] = (f32x4){0.f, 0.f, 0.f, 0.f};

    #pragma unroll
    for (int kc = 0; kc < 4; ++kc) {
        #pragma unroll
        for (int nt = 0; nt < 8; ++nt) {
            short8 b = *(const short8*)(Wt + (nt * 16 + ln) * 128 + kc * 32 + g * 8);
            acc[nt] = __builtin_amdgcn_mfma_f32_16x16x32_bf16(af[kc], b, acc[nt], 0, 0, 0);
        }
    }

    #pragma unroll
    for (int nt = 0; nt < 8; ++nt) {
        int col = nt * 16 + ln;
        float bv = bias[col];
        #pragma unroll
        for (int r = 0; r < 4; ++r) {
            int row = rowBase + g * 4 + r;   // C/D: row=(lane>>4)*4+reg, col=lane&15
            if (row < M) {
                size_t o = (size_t)row * 128 + col;
                float v = acc[nt][r] + bv;
                if constexpr (MODE == 0) {
                    of32[o] = silu_f(v);
                } else if constexpr (MODE == 1) {
                    float rb = 0.f;
                    const float* rr = aux0 + (size_t)row * 6;
                    #pragma unroll
                    for (int q = 0; q < 6; ++q) rb += rr[q] * aux1[q * 128 + col];
                    ob16[o] = f2bf(silu_f(v) * rb);
                } else if constexpr (MODE == 2) {
                    ob16[o] = f2bf(silu_f(v));
                } else if constexpr (MODE == 3) {
                    float nv = hbuf[o] + silu_f(v);
                    hbuf[o] = nv; ob16[o] = f2bf(nv);
                } else if constexpr (MODE == 4) {
                    float nv = silu_f(v) + aux0[o];
                    hbuf[o] = nv; ob16[o] = f2bf(nv);
                } else {
                    of32[o] = silu_f(v);
                }
            }
        }
    }
}

// ---------- launch ----------
extern "C" void kernel_launch(void* const* d_in, const int* in_sizes, int n_in,
                              void* d_out, int out_size, void* d_ws, size_t ws_size,
                              hipStream_t stream) {
    const float* x      = (const float*)d_in[0];
    const float* rbf    = (const float*)d_in[1];
    const float* sbf    = (const float*)d_in[2];
    const int*   idx_kj = (const int*)d_in[3];
    const int*   idx_ji = (const int*)d_in[4];
    const float* W_rbf  = (const float*)d_in[5];
    const float* W_sbf  = (const float*)d_in[6];
    const float* Wkj    = (const float*)d_in[7];
    const float* bkj    = (const float*)d_in[8];
    const float* Wji    = (const float*)d_in[9];
    const float* bji    = (const float*)d_in[10];
    const float* Wbil   = (const float*)d_in[11];
    const float* bW1    = (const float*)d_in[12];
    const float* bb1    = (const float*)d_in[13];
    const float* bW2    = (const float*)d_in[14];
    const float* bb2    = (const float*)d_in[15];
    const float* Wlin   = (const float*)d_in[16];
    const float* blin   = (const float*)d_in[17];
    const float* aW1    = (const float*)d_in[18];
    const float* ab1    = (const float*)d_in[19];
    const float* aW2    = (const float*)d_in[20];
    const float* ab2    = (const float*)d_in[21];
    const float* Wout   = (const float*)d_in[22];
    const float* bout   = (const float*)d_in[23];
    float* out = (float*)d_out;

    char* ws = (char*)d_ws;
    size_t off = 0;
    auto alloc = [&](size_t bytes) { char* p = ws + off; off += bytes; return p; };
    short* y    = (short*)alloc((size_t)NEDGE * 1024 * 2);   // 102.4 MB
    short* xkj  = (short*)alloc((size_t)NEDGE * 128 * 2);
    short* hb   = (short*)alloc((size_t)NEDGE * 128 * 2);
    short* tb   = (short*)alloc((size_t)NEDGE * 128 * 2);
    float* sbfh = (float*)alloc((size_t)NTRI * 8 * 4);
    float* xji  = (float*)alloc((size_t)NEDGE * 128 * 4);
    float* h    = (float*)alloc((size_t)NEDGE * 128 * 4);
    short* WbT  = (short*)alloc((size_t)131072 * 2);
    short* Wt[10];
    for (int i = 0; i < 10; ++i) Wt[i] = (short*)alloc((size_t)16384 * 2);
    int* counts = (int*)alloc((size_t)NEDGE * 4);
    int* partial= (int*)alloc((size_t)NEDGE * 4);
    int* rowptr = (int*)alloc((size_t)NEDGE * 4);
    int* wcur   = (int*)alloc((size_t)NEDGE * 4);
    int* bsum   = (int*)alloc(256 * 4);
    int* perm   = (int*)alloc((size_t)NTRI * 4);
    short* xb   = y;   // alias: xb [E,128] bf16 dead before ybuild writes y
    (void)ws_size; (void)n_in; (void)in_sizes; (void)out_size;

    hipMemsetAsync(counts, 0, (size_t)NEDGE * 4, stream);

    cvt_kernel<<<dim3((NEDGE * 128 / 4 + 255) / 256), 256, 0, stream>>>(x, xb, NEDGE * 128 / 4);
    cvt_kernel<<<dim3((131072 / 4 + 255) / 256), 256, 0, stream>>>(Wbil, WbT, 131072 / 4);

    TP tp;
    const float* srcs[10] = {Wkj, Wji, bW1, bW2, Wlin, aW1, aW1 + 16384, aW2, aW2 + 16384, Wout};
    for (int i = 0; i < 10; ++i) { tp.s[i] = srcs[i]; tp.d[i] = Wt[i]; }
    t128_all<<<dim3(64, 10), 256, 0, stream>>>(tp);

    sbfh_kernel<<<dim3((NTRI * 8 + 255) / 256), 256, 0, stream>>>(sbf, W_sbf, sbfh);

    // CSR of idx_ji
    int NB1 = (NEDGE + 255) / 256;   // 196
    hist_kernel<<<dim3((NTRI + 255) / 256), 256, 0, stream>>>(idx_ji, counts);
    scan1_kernel<<<dim3(NB1), 256, 0, stream>>>(counts, partial, bsum);
    scan2_kernel<<<dim3(1), 256, 0, stream>>>(bsum, NB1);
    scan3_kernel<<<dim3(NB1), 256, 0, stream>>>(partial, bsum, rowptr, wcur);
    scatter_kernel<<<dim3((NTRI + 255) / 256), 256, 0, stream>>>(idx_ji, wcur, perm);

    int gE = (NEDGE + 63) / 64;
    // x_ji = silu(x @ Wji + bji) -> f32
    gemm128<0><<<gE, 256, 0, stream>>>(xb, Wt[1], bji, NEDGE, xji, nullptr, nullptr, nullptr, nullptr);
    // x_kj = silu(x @ Wkj + bkj) * (rbf @ W_rbf) -> bf16
    gemm128<1><<<gE, 256, 0, stream>>>(xb, Wt[0], bkj, NEDGE, nullptr, xkj, rbf, W_rbf, nullptr);

    // y build (overwrites xb alias region — xb is dead now)
    ybuild_kernel<<<dim3(NEDGE), 128, 0, stream>>>(xkj, sbfh, idx_kj, rowptr, counts, perm, y);

    // h = x_ji + y @ Wbil ; also emits hb = bf16(h)
    ygemm_kernel<<<gE, 256, 0, stream>>>(y, WbT, xji, h, hb);

    // before residual block
    gemm128<2><<<gE, 256, 0, stream>>>(hb, Wt[2], bb1, NEDGE, nullptr, tb, nullptr, nullptr, nullptr);
    gemm128<3><<<gE, 256, 0, stream>>>(tb, Wt[3], bb2, NEDGE, nullptr, hb, nullptr, nullptr, h);
    // h = silu(h @ Wlin + blin) + x
    gemm128<4><<<gE, 256, 0, stream>>>(hb, Wt[4], blin, NEDGE, nullptr, hb, x, nullptr, h);
    // after residual block 0
    gemm128<2><<<gE, 256, 0, stream>>>(hb, Wt[5], ab1, NEDGE, nullptr, tb, nullptr, nullptr, nullptr);
    gemm128<3><<<gE, 256, 0, stream>>>(tb, Wt[7], ab2, NEDGE, nullptr, hb, nullptr, nullptr, h);
    // after residual block 1
    gemm128<2><<<gE, 256, 0, stream>>>(hb, Wt[6], ab1 + 128, NEDGE, nullptr, tb, nullptr, nullptr, nullptr);
    gemm128<3><<<gE, 256, 0, stream>>>(tb, Wt[8], ab2 + 128, NEDGE, nullptr, hb, nullptr, nullptr, h);
    // out = silu(h @ Wout + bout)
    gemm128<5><<<gE, 256, 0, stream>>>(hb, Wt[9], bout, NEDGE, out, nullptr, nullptr, nullptr, nullptr);
}

// Round 3
// 579.740 us; speedup vs baseline: 1.2268x; 1.1535x over previous
//
#include <hip/hip_runtime.h>
#include <hip/hip_bf16.h>

// DimeNet InteractionBlock for MI355X (gfx950).
#define NEDGE 50000
#define NTRI 200000

typedef __attribute__((ext_vector_type(8))) short short8;   // 8 bf16 (4 VGPRs) — MFMA A/B frag
typedef __attribute__((ext_vector_type(4))) short short4v;
typedef __attribute__((ext_vector_type(4))) float f32x4;    // MFMA C/D frag

__device__ __forceinline__ float silu_f(float v) { return v / (1.0f + __expf(-v)); }

// f32 -> bf16 bits, round-to-nearest-even
__device__ __forceinline__ short f2bf(float f) {
    unsigned u = __float_as_uint(f);
    unsigned r = (u + 0x7FFFu + ((u >> 16) & 1u)) >> 16;
    return (short)r;
}
__device__ __forceinline__ float bf2f(short s) {
    return __uint_as_float(((unsigned)(unsigned short)s) << 16);
}

// ---------- prep kernels ----------

__global__ void cvt_kernel(const float* __restrict__ src, short* __restrict__ dst, int n4) {
    int i = blockIdx.x * 256 + threadIdx.x;
    if (i < n4) {
        float4 v = ((const float4*)src)[i];
        short4v o;
        o[0] = f2bf(v.x); o[1] = f2bf(v.y); o[2] = f2bf(v.z); o[3] = f2bf(v.w);
        ((short4v*)dst)[i] = o;
    }
}

// 10x 128x128 transpose+convert: dst[n*128+k] = bf16(src[k*128+n])
struct TP { const float* s[10]; short* d[10]; };
__global__ void t128_all(TP p) {
    const float* __restrict__ src = p.s[blockIdx.y];
    short* __restrict__ dst = p.d[blockIdx.y];
    int i = blockIdx.x * 256 + threadIdx.x;    // grid.x = 64 -> 16384 exactly
    int k = i >> 7, n = i & 127;
    dst[n * 128 + k] = f2bf(src[i]);
}

// sbf_h = sbf @ W_sbf : [T,42]@[42,8] -> f32 [T,8]; 32 rows/block, LDS-staged
__global__ __launch_bounds__(256) void sbfh_kernel(const float* __restrict__ sbf,
                                                   const float* __restrict__ Wsbf,
                                                   float* __restrict__ out) {
    __shared__ float s[32 * 42];
    __shared__ float w[42 * 8];
    int tid = threadIdx.x;
    size_t base = (size_t)blockIdx.x * 32;          // 200000/32 = 6250 exact
    for (int u = tid; u < 32 * 42; u += 256) s[u] = sbf[base * 42 + u];
    for (int u = tid; u < 42 * 8; u += 256) w[u] = Wsbf[u];
    __syncthreads();
    int row = tid >> 3, j = tid & 7;
    float acc = 0.f;
    #pragma unroll
    for (int k = 0; k < 42; ++k) acc += s[row * 42 + k] * w[k * 8 + j];
    out[base * 8 + tid] = acc;
}

// ---------- CSR build for idx_ji ----------

__global__ void hist_kernel(const int* __restrict__ ji, int* __restrict__ counts) {
    int i = blockIdx.x * 256 + threadIdx.x;
    if (i < NTRI) atomicAdd(&counts[ji[i]], 1);
}

__global__ void scan1_kernel(const int* __restrict__ counts, int* __restrict__ partial,
                             int* __restrict__ bsum) {
    __shared__ int tmp[256];
    int tid = threadIdx.x;
    int i = blockIdx.x * 256 + tid;
    int v = (i < NEDGE) ? counts[i] : 0;
    tmp[tid] = v; __syncthreads();
    #pragma unroll
    for (int o = 1; o < 256; o <<= 1) {
        int t = (tid >= o) ? tmp[tid - o] : 0;
        __syncthreads();
        tmp[tid] += t;
        __syncthreads();
    }
    if (i < NEDGE) partial[i] = tmp[tid] - v;
    if (tid == 255) bsum[blockIdx.x] = tmp[255];
}

__global__ void scan2_kernel(int* __restrict__ bsum, int nb) {
    __shared__ int tmp[256];
    int tid = threadIdx.x;
    int v = (tid < nb) ? bsum[tid] : 0;
    tmp[tid] = v; __syncthreads();
    #pragma unroll
    for (int o = 1; o < 256; o <<= 1) {
        int t = (tid >= o) ? tmp[tid - o] : 0;
        __syncthreads();
        tmp[tid] += t;
        __syncthreads();
    }
    if (tid < nb) bsum[tid] = tmp[tid] - v;
}

__global__ void scan3_kernel(const int* __restrict__ partial, const int* __restrict__ bsum,
                             int* __restrict__ rowptr, int* __restrict__ wcur) {
    int i = blockIdx.x * 256 + threadIdx.x;
    if (i < NEDGE) {
        int r = partial[i] + bsum[blockIdx.x];
        rowptr[i] = r;
        wcur[i] = r;
    }
}

__global__ void scatter_kernel(const int* __restrict__ ji, int* __restrict__ wcur,
                               int* __restrict__ perm) {
    int w = blockIdx.x * 256 + threadIdx.x;
    if (w < NTRI) {
        int p = atomicAdd(&wcur[ji[w]], 1);
        perm[p] = w;
    }
}

// ---------- fused bilinear: build y-tile in LDS, GEMM vs WbT, epilogue h = xji + acc ----------
// y[e, j*128+l] = sum_{w in CSR(e)} sbf_h[w,j] * x_kj[idx_kj[w], l]   (built in LDS, bf16)
// h[e, i] = xji[e, i] + sum_k y[e,k] * WbT[i*1024+k]
__global__ __launch_bounds__(512) void bilinear_fused(
    const short* __restrict__ xkj, const float* __restrict__ sbfh,
    const int* __restrict__ idx_kj, const int* __restrict__ rowptr,
    const int* __restrict__ counts, const int* __restrict__ perm,
    const float* __restrict__ xji, const short* __restrict__ WbT,
    float* __restrict__ h, short* __restrict__ hb)
{
    __shared__ __align__(16) short ylds[64 * 1024];  // 128 KB, XOR-swizzled rows (2048B)
    __shared__ __align__(16) short blds[128 * 64];   // 16 KB WbT k-chunk, swizzled (128B rows)

    int tid = threadIdx.x;
    int e0 = blockIdx.x * 64;
    int team = tid >> 7;          // 0..3 (2 waves each)
    int i = tid & 127;            // column l

    // ---- build phase: 4 edges concurrently x 16 rounds ----
    for (int r = 0; r < 16; ++r) {
        int e_loc = r * 4 + team;
        int e = e0 + e_loc;
        float acc[8];
        #pragma unroll
        for (int j = 0; j < 8; ++j) acc[j] = 0.f;
        if (e < NEDGE) {
            int p0 = __builtin_amdgcn_readfirstlane(rowptr[e]);
            int n  = __builtin_amdgcn_readfirstlane(counts[e]);
            for (int t0 = 0; t0 < n; t0 += 4) {
                int m = n - t0;
                int wq[4], kq[4];
                #pragma unroll
                for (int t = 0; t < 4; ++t)
                    wq[t] = (t < m) ? perm[p0 + t0 + t] : 0;
                #pragma unroll
                for (int t = 0; t < 4; ++t) {
                    wq[t] = __builtin_amdgcn_readfirstlane(wq[t]);
                    kq[t] = (t < m) ? idx_kj[wq[t]] : 0;
                }
                #pragma unroll
                for (int t = 0; t < 4; ++t) {
                    if (t < m) {
                        int kj = __builtin_amdgcn_readfirstlane(kq[t]);
                        float xv = bf2f(xkj[(size_t)kj * 128 + i]);
                        float4 s0 = *(const float4*)(sbfh + (size_t)wq[t] * 8);
                        float4 s1 = *(const float4*)(sbfh + (size_t)wq[t] * 8 + 4);
                        acc[0] += s0.x * xv; acc[1] += s0.y * xv;
                        acc[2] += s0.z * xv; acc[3] += s0.w * xv;
                        acc[4] += s1.x * xv; acc[5] += s1.y * xv;
                        acc[6] += s1.z * xv; acc[7] += s1.w * xv;
                    }
                }
            }
        }
        unsigned rowbase = (unsigned)(e_loc * 2048);
        unsigned xr = (unsigned)((e_loc & 7) << 4);
        #pragma unroll
        for (int j = 0; j < 8; ++j) {
            unsigned bo = (rowbase + (unsigned)((j * 128 + i) * 2)) ^ xr;
            *(short*)((char*)ylds + bo) = f2bf(acc[j]);
        }
    }

    // ---- GEMM phase: [64,1024] @ [1024,128], 8 waves ----
    int wv = tid >> 6, lane = tid & 63, g = lane >> 4, ln = lane & 15;
    int rt = wv >> 1, ch = wv & 1;     // row-tile 0..3, col-half 0..1
    f32x4 acc4[4];
    #pragma unroll
    for (int nt = 0; nt < 4; ++nt) acc4[nt] = (f32x4){0.f, 0.f, 0.f, 0.f};

    for (int c = 0; c < 16; ++c) {     // K chunks of 64
        __syncthreads();               // (first one also fences the build ds_writes)
        #pragma unroll
        for (int q = 0; q < 2; ++q) {  // stage blds: 1024 x 16B chunks
            int idx = tid + q * 512;
            int bi = idx >> 3, bc = idx & 7;    // row i, 16B-chunk
            unsigned bo = (unsigned)(bi * 128 + bc * 16) ^ (unsigned)((bi & 7) << 4);
            *(short8*)((char*)blds + bo) = *(const short8*)(WbT + (size_t)bi * 1024 + c * 64 + bc * 8);
        }
        __syncthreads();
        #pragma unroll
        for (int kk = 0; kk < 2; ++kk) {
            int row = rt * 16 + ln;
            unsigned ab = ((unsigned)(row * 2048 + (c * 64 + kk * 32 + g * 8) * 2))
                          ^ ((unsigned)((row & 7) << 4));
            short8 a = *(short8*)((char*)ylds + ab);
            #pragma unroll
            for (int nt = 0; nt < 4; ++nt) {
                int bi = ch * 64 + nt * 16 + ln;
                unsigned bb = ((unsigned)(bi * 128 + kk * 64 + g * 16))
                              ^ ((unsigned)((bi & 7) << 4));
                short8 b = *(short8*)((char*)blds + bb);
                acc4[nt] = __builtin_amdgcn_mfma_f32_16x16x32_bf16(a, b, acc4[nt], 0, 0, 0);
            }
        }
    }

    // epilogue: h = xji + acc, hb = bf16(h)
    #pragma unroll
    for (int nt = 0; nt < 4; ++nt) {
        int col = ch * 64 + nt * 16 + ln;
        #pragma unroll
        for (int r2 = 0; r2 < 4; ++r2) {
            int e = e0 + rt * 16 + g * 4 + r2;   // C/D: row=(lane>>4)*4+reg, col=lane&15
            if (e < NEDGE) {
                size_t o = (size_t)e * 128 + col;
                float v = acc4[nt][r2] + xji[o];
                h[o] = v; hb[o] = f2bf(v);
            }
        }
    }
}

// ---------- generic [M,128] @ [128,128] bf16 MFMA GEMM, B staged in LDS ----------
// MODE 0: of32 = silu(acc+bias)                          (x_ji)
// MODE 1: ob16 = bf16(silu(acc+bias) * (rbf@W_rbf))      (x_kj; aux0=rbf, aux1=W_rbf)
// MODE 2: ob16 = bf16(silu(acc+bias))                    (t of residual MLP)
// MODE 3: h += silu(acc+bias); ob16 = bf16(h)            (residual second half; hbuf=h)
// MODE 4: h = silu(acc+bias) + aux0; ob16 = bf16(h)      (lin + x residual; aux0=x f32)
// MODE 5: of32 = silu(acc+bias)                          (final out)
template<int MODE>
__global__ __launch_bounds__(256) void gemm128(
    const short* __restrict__ A, const short* __restrict__ Wt,
    const float* __restrict__ bias, int M,
    float* __restrict__ of32, short* __restrict__ ob16,
    const float* __restrict__ aux0, const float* __restrict__ aux1,
    float* __restrict__ hbuf)
{
    __shared__ __align__(16) short wlds[128 * 128];   // 32 KB, swizzled (256B rows)
    int tid = threadIdx.x;
    int wave = tid >> 6, lane = tid & 63;
    int g = lane >> 4, ln = lane & 15;
    int rowBase = blockIdx.x * 64 + wave * 16;

    // stage Wt -> LDS (each thread 8 x 16B; per-wave contiguous 1KB)
    #pragma unroll
    for (int q = 0; q < 8; ++q) {
        int idx = tid + q * 256;                   // 0..2047
        int wi = idx >> 4, wc = idx & 15;
        unsigned bo = (unsigned)(wi * 256 + wc * 16) ^ (unsigned)((wi & 7) << 4);
        *(short8*)((char*)wlds + bo) = *(const short8*)(Wt + wi * 128 + wc * 8);
    }

    int arow = rowBase + ln; if (arow > M - 1) arow = M - 1;
    const short8* Ar = (const short8*)(A + (size_t)arow * 128);
    short8 af[4];
    #pragma unroll
    for (int kc = 0; kc < 4; ++kc) af[kc] = Ar[kc * 4 + g];   // k = kc*32 + g*8 + e

    __syncthreads();

    f32x4 acc[8];
    #pragma unroll
    for (int nt = 0; nt < 8; ++nt) acc[nt] = (f32x4){0.f, 0.f, 0.f, 0.f};

    #pragma unroll
    for (int kc = 0; kc < 4; ++kc) {
        #pragma unroll
        for (int nt = 0; nt < 8; ++nt) {
            int wi = nt * 16 + ln;
            unsigned bo = (unsigned)(wi * 256 + kc * 64 + g * 16) ^ (unsigned)((wi & 7) << 4);
            short8 b = *(short8*)((char*)wlds + bo);
            acc[nt] = __builtin_amdgcn_mfma_f32_16x16x32_bf16(af[kc], b, acc[nt], 0, 0, 0);
        }
    }

    #pragma unroll
    for (int nt = 0; nt < 8; ++nt) {
        int col = nt * 16 + ln;
        float bv = bias[col];
        #pragma unroll
        for (int r = 0; r < 4; ++r) {
            int row = rowBase + g * 4 + r;   // C/D: row=(lane>>4)*4+reg, col=lane&15
            if (row < M) {
                size_t o = (size_t)row * 128 + col;
                float v = acc[nt][r] + bv;
                if constexpr (MODE == 0) {
                    of32[o] = silu_f(v);
                } else if constexpr (MODE == 1) {
                    float rb = 0.f;
                    const float* rr = aux0 + (size_t)row * 6;
                    #pragma unroll
                    for (int q = 0; q < 6; ++q) rb += rr[q] * aux1[q * 128 + col];
                    ob16[o] = f2bf(silu_f(v) * rb);
                } else if constexpr (MODE == 2) {
                    ob16[o] = f2bf(silu_f(v));
                } else if constexpr (MODE == 3) {
                    float nv = hbuf[o] + silu_f(v);
                    hbuf[o] = nv; ob16[o] = f2bf(nv);
                } else if constexpr (MODE == 4) {
                    float nv = silu_f(v) + aux0[o];
                    hbuf[o] = nv; ob16[o] = f2bf(nv);
                } else {
                    of32[o] = silu_f(v);
                }
            }
        }
    }
}

// ---------- launch ----------
extern "C" void kernel_launch(void* const* d_in, const int* in_sizes, int n_in,
                              void* d_out, int out_size, void* d_ws, size_t ws_size,
                              hipStream_t stream) {
    const float* x      = (const float*)d_in[0];
    const float* rbf    = (const float*)d_in[1];
    const float* sbf    = (const float*)d_in[2];
    const int*   idx_kj = (const int*)d_in[3];
    const int*   idx_ji = (const int*)d_in[4];
    const float* W_rbf  = (const float*)d_in[5];
    const float* W_sbf  = (const float*)d_in[6];
    const float* Wkj    = (const float*)d_in[7];
    const float* bkj    = (const float*)d_in[8];
    const float* Wji    = (const float*)d_in[9];
    const float* bji    = (const float*)d_in[10];
    const float* Wbil   = (const float*)d_in[11];
    const float* bW1    = (const float*)d_in[12];
    const float* bb1    = (const float*)d_in[13];
    const float* bW2    = (const float*)d_in[14];
    const float* bb2    = (const float*)d_in[15];
    const float* Wlin   = (const float*)d_in[16];
    const float* blin   = (const float*)d_in[17];
    const float* aW1    = (const float*)d_in[18];
    const float* ab1    = (const float*)d_in[19];
    const float* aW2    = (const float*)d_in[20];
    const float* ab2    = (const float*)d_in[21];
    const float* Wout   = (const float*)d_in[22];
    const float* bout   = (const float*)d_in[23];
    float* out = (float*)d_out;

    char* ws = (char*)d_ws;
    size_t off = 0;
    auto alloc = [&](size_t bytes) { char* p = ws + off; off += bytes; return p; };
    short* xb   = (short*)alloc((size_t)NEDGE * 128 * 2);
    short* xkj  = (short*)alloc((size_t)NEDGE * 128 * 2);
    short* hb   = (short*)alloc((size_t)NEDGE * 128 * 2);
    short* tb   = (short*)alloc((size_t)NEDGE * 128 * 2);
    float* sbfh = (float*)alloc((size_t)NTRI * 8 * 4);
    float* xji  = (float*)alloc((size_t)NEDGE * 128 * 4);
    float* h    = (float*)alloc((size_t)NEDGE * 128 * 4);
    short* WbT  = (short*)alloc((size_t)131072 * 2);
    short* Wt[10];
    for (int i = 0; i < 10; ++i) Wt[i] = (short*)alloc((size_t)16384 * 2);
    int* counts = (int*)alloc((size_t)NEDGE * 4);
    int* partial= (int*)alloc((size_t)NEDGE * 4);
    int* rowptr = (int*)alloc((size_t)NEDGE * 4);
    int* wcur   = (int*)alloc((size_t)NEDGE * 4);
    int* bsum   = (int*)alloc(256 * 4);
    int* perm   = (int*)alloc((size_t)NTRI * 4);
    (void)ws_size; (void)n_in; (void)in_sizes; (void)out_size;

    hipMemsetAsync(counts, 0, (size_t)NEDGE * 4, stream);

    cvt_kernel<<<dim3((NEDGE * 128 / 4 + 255) / 256), 256, 0, stream>>>(x, xb, NEDGE * 128 / 4);
    cvt_kernel<<<dim3((131072 / 4 + 255) / 256), 256, 0, stream>>>(Wbil, WbT, 131072 / 4);

    TP tp;
    const float* srcs[10] = {Wkj, Wji, bW1, bW2, Wlin, aW1, aW1 + 16384, aW2, aW2 + 16384, Wout};
    for (int i = 0; i < 10; ++i) { tp.s[i] = srcs[i]; tp.d[i] = Wt[i]; }
    t128_all<<<dim3(64, 10), 256, 0, stream>>>(tp);

    sbfh_kernel<<<dim3(NTRI / 32), 256, 0, stream>>>(sbf, W_sbf, sbfh);

    // CSR of idx_ji
    int NB1 = (NEDGE + 255) / 256;   // 196
    hist_kernel<<<dim3((NTRI + 255) / 256), 256, 0, stream>>>(idx_ji, counts);
    scan1_kernel<<<dim3(NB1), 256, 0, stream>>>(counts, partial, bsum);
    scan2_kernel<<<dim3(1), 256, 0, stream>>>(bsum, NB1);
    scan3_kernel<<<dim3(NB1), 256, 0, stream>>>(partial, bsum, rowptr, wcur);
    scatter_kernel<<<dim3((NTRI + 255) / 256), 256, 0, stream>>>(idx_ji, wcur, perm);

    int gE = (NEDGE + 63) / 64;   // 782
    // x_ji = silu(x @ Wji + bji) -> f32
    gemm128<0><<<gE, 256, 0, stream>>>(xb, Wt[1], bji, NEDGE, xji, nullptr, nullptr, nullptr, nullptr);
    // x_kj = silu(x @ Wkj + bkj) * (rbf @ W_rbf) -> bf16
    gemm128<1><<<gE, 256, 0, stream>>>(xb, Wt[0], bkj, NEDGE, nullptr, xkj, rbf, W_rbf, nullptr);

    // fused bilinear + segment-sum + h0: h = xji + (y @ Wbil), hb = bf16(h)
    bilinear_fused<<<gE, 512, 0, stream>>>(xkj, sbfh, idx_kj, rowptr, counts, perm,
                                           xji, WbT, h, hb);

    // before residual block
    gemm128<2><<<gE, 256, 0, stream>>>(hb, Wt[2], bb1, NEDGE, nullptr, tb, nullptr, nullptr, nullptr);
    gemm128<3><<<gE, 256, 0, stream>>>(tb, Wt[3], bb2, NEDGE, nullptr, hb, nullptr, nullptr, h);
    // h = silu(h @ Wlin + blin) + x
    gemm128<4><<<gE, 256, 0, stream>>>(hb, Wt[4], blin, NEDGE, nullptr, hb, x, nullptr, h);
    // after residual block 0
    gemm128<2><<<gE, 256, 0, stream>>>(hb, Wt[5], ab1, NEDGE, nullptr, tb, nullptr, nullptr, nullptr);
    gemm128<3><<<gE, 256, 0, stream>>>(tb, Wt[7], ab2, NEDGE, nullptr, hb, nullptr, nullptr, h);
    // after residual block 1
    gemm128<2><<<gE, 256, 0, stream>>>(hb, Wt[6], ab1 + 128, NEDGE, nullptr, tb, nullptr, nullptr, nullptr);
    gemm128<3><<<gE, 256, 0, stream>>>(tb, Wt[8], ab2 + 128, NEDGE, nullptr, hb, nullptr, nullptr, h);
    // out = silu(h @ Wout + bout)
    gemm128<5><<<gE, 256, 0, stream>>>(hb, Wt[9], bout, NEDGE, out, nullptr, nullptr, nullptr, nullptr);
}

// Round 4
// 357.703 us; speedup vs baseline: 1.9883x; 1.6207x over previous
//
#include <hip/hip_runtime.h>
#include <hip/hip_bf16.h>

// DimeNet InteractionBlock for MI355X (gfx950).
#define NEDGE 50000
#define NTRI 200000

typedef __attribute__((ext_vector_type(8))) short short8;   // 8 bf16 (4 VGPRs) — MFMA A/B frag
typedef __attribute__((ext_vector_type(4))) short short4v;
typedef __attribute__((ext_vector_type(4))) float f32x4;    // MFMA C/D frag

__device__ __forceinline__ float silu_f(float v) { return v / (1.0f + __expf(-v)); }

// f32 -> bf16 bits, round-to-nearest-even
__device__ __forceinline__ short f2bf(float f) {
    unsigned u = __float_as_uint(f);
    unsigned r = (u + 0x7FFFu + ((u >> 16) & 1u)) >> 16;
    return (short)r;
}
__device__ __forceinline__ float bf2f(short s) {
    return __uint_as_float(((unsigned)(unsigned short)s) << 16);
}

// ---------- prep kernels ----------

__global__ void cvt_kernel(const float* __restrict__ src, short* __restrict__ dst, int n4) {
    int i = blockIdx.x * 256 + threadIdx.x;
    if (i < n4) {
        float4 v = ((const float4*)src)[i];
        short4v o;
        o[0] = f2bf(v.x); o[1] = f2bf(v.y); o[2] = f2bf(v.z); o[3] = f2bf(v.w);
        ((short4v*)dst)[i] = o;
    }
}

// 10x 128x128 transpose+convert: dst[n*128+k] = bf16(src[k*128+n])
struct TP { const float* s[10]; short* d[10]; };
__global__ void t128_all(TP p) {
    const float* __restrict__ src = p.s[blockIdx.y];
    short* __restrict__ dst = p.d[blockIdx.y];
    int i = blockIdx.x * 256 + threadIdx.x;    // grid.x = 64 -> 16384 exactly
    int k = i >> 7, n = i & 127;
    dst[n * 128 + k] = f2bf(src[i]);
}

// sbf_h = sbf @ W_sbf : [T,42]@[42,8] -> f32 [T,8]; 32 rows/block, LDS-staged
__global__ __launch_bounds__(256) void sbfh_kernel(const float* __restrict__ sbf,
                                                   const float* __restrict__ Wsbf,
                                                   float* __restrict__ out) {
    __shared__ float s[32 * 42];
    __shared__ float w[42 * 8];
    int tid = threadIdx.x;
    size_t base = (size_t)blockIdx.x * 32;          // 200000/32 = 6250 exact
    for (int u = tid; u < 32 * 42; u += 256) s[u] = sbf[base * 42 + u];
    for (int u = tid; u < 42 * 8; u += 256) w[u] = Wsbf[u];
    __syncthreads();
    int row = tid >> 3, j = tid & 7;
    float acc = 0.f;
    #pragma unroll
    for (int k = 0; k < 42; ++k) acc += s[row * 42 + k] * w[k * 8 + j];
    out[base * 8 + tid] = acc;
}

// ---------- CSR build for idx_ji ----------

__global__ void hist_kernel(const int* __restrict__ ji, int* __restrict__ counts) {
    int i = blockIdx.x * 256 + threadIdx.x;
    if (i < NTRI) atomicAdd(&counts[ji[i]], 1);
}

__global__ void scan1_kernel(const int* __restrict__ counts, int* __restrict__ partial,
                             int* __restrict__ bsum) {
    __shared__ int tmp[256];
    int tid = threadIdx.x;
    int i = blockIdx.x * 256 + tid;
    int v = (i < NEDGE) ? counts[i] : 0;
    tmp[tid] = v; __syncthreads();
    #pragma unroll
    for (int o = 1; o < 256; o <<= 1) {
        int t = (tid >= o) ? tmp[tid - o] : 0;
        __syncthreads();
        tmp[tid] += t;
        __syncthreads();
    }
    if (i < NEDGE) partial[i] = tmp[tid] - v;
    if (tid == 255) bsum[blockIdx.x] = tmp[255];
}

__global__ void scan2_kernel(int* __restrict__ bsum, int nb) {
    __shared__ int tmp[256];
    int tid = threadIdx.x;
    int v = (tid < nb) ? bsum[tid] : 0;
    tmp[tid] = v; __syncthreads();
    #pragma unroll
    for (int o = 1; o < 256; o <<= 1) {
        int t = (tid >= o) ? tmp[tid - o] : 0;
        __syncthreads();
        tmp[tid] += t;
        __syncthreads();
    }
    if (tid < nb) bsum[tid] = tmp[tid] - v;
}

__global__ void scan3_kernel(const int* __restrict__ partial, const int* __restrict__ bsum,
                             int* __restrict__ rowptr, int* __restrict__ wcur) {
    int i = blockIdx.x * 256 + threadIdx.x;
    if (i < NEDGE) {
        int r = partial[i] + bsum[blockIdx.x];
        rowptr[i] = r;
        wcur[i] = r;
    }
}

__global__ void scatter_kernel(const int* __restrict__ ji, int* __restrict__ wcur,
                               int* __restrict__ perm) {
    int w = blockIdx.x * 256 + threadIdx.x;
    if (w < NTRI) {
        int p = atomicAdd(&wcur[ji[w]], 1);
        perm[p] = w;
    }
}

// CSR-order the triplet payloads: one coalesced stream for the build phase.
__global__ void permute_kernel(const int* __restrict__ perm, const int* __restrict__ idx_kj,
                               const float* __restrict__ sbfh, int* __restrict__ kjp,
                               float* __restrict__ sbfhp) {
    int p = blockIdx.x * 256 + threadIdx.x;
    if (p < NTRI) {
        int w = perm[p];
        kjp[p] = idx_kj[w];
        float4 a = *(const float4*)(sbfh + (size_t)w * 8);
        float4 b = *(const float4*)(sbfh + (size_t)w * 8 + 4);
        *(float4*)(sbfhp + (size_t)p * 8) = a;
        *(float4*)(sbfhp + (size_t)p * 8 + 4) = b;
    }
}

// ---------- fused bilinear: build 32-edge y-tile in LDS, GEMM vs WbT, h = xji + acc ----------
// y[e, j*128+l] = sum_{w in CSR(e)} sbf_h[w,j] * x_kj[idx_kj[w], l]
// h[e, i] = xji[e, i] + sum_k y[e,k] * WbT[i*1024+k]
#define BE 32
__global__ __launch_bounds__(512) void bilinear_fused(
    const short* __restrict__ xkj, const float* __restrict__ sbfhp,
    const int* __restrict__ kjp, const int* __restrict__ rowptr,
    const int* __restrict__ counts,
    const float* __restrict__ xji, const short* __restrict__ WbT,
    float* __restrict__ h, short* __restrict__ hb)
{
    __shared__ __align__(16) short ylds[BE * 1024];  // 64 KB, XOR-swizzled rows (2048B)
    __shared__ __align__(16) short blds[128 * 64];   // 16 KB WbT k-chunk, swizzled (128B rows)

    int tid = threadIdx.x;
    int e0 = blockIdx.x * BE;
    int wv = tid >> 6, lane = tid & 63, g = lane >> 4, ln = lane & 15;

    // per-wave: fetch the block's 32 (p0, n) pairs coalesced, then shfl
    int eidx = e0 + ((lane < BE) ? lane : BE - 1);
    if (eidx > NEDGE - 1) eidx = NEDGE - 1;
    int rp_l = rowptr[eidx];
    int ct_l = counts[eidx];

    // ---- build phase: wave wv builds edges wv*4 .. wv*4+4 ----
    for (int es = 0; es < 4; ++es) {
        int e_loc = wv * 4 + es;
        int e = e0 + e_loc;
        float accA[8], accB[8];
        #pragma unroll
        for (int j = 0; j < 8; ++j) { accA[j] = 0.f; accB[j] = 0.f; }
        if (e < NEDGE) {
            int p0 = __builtin_amdgcn_readfirstlane(__shfl(rp_l, e_loc));
            int n  = __builtin_amdgcn_readfirstlane(__shfl(ct_l, e_loc));
            for (int tc = 0; tc < n; tc += 64) {
                int mm = n - tc; if (mm > 64) mm = 64;
                int li = (lane < mm) ? lane : mm - 1;
                int kt = kjp[p0 + tc + li];              // one coalesced load
                for (int tb = 0; tb < mm; tb += 4) {
                    int m4 = mm - tb; if (m4 > 4) m4 = 4;
                    int i1 = tb + 1 < mm ? tb + 1 : mm - 1;
                    int i2 = tb + 2 < mm ? tb + 2 : mm - 1;
                    int i3 = tb + 3 < mm ? tb + 3 : mm - 1;
                    int k0 = __shfl(kt, tb), k1 = __shfl(kt, i1);
                    int k2 = __shfl(kt, i2), k3 = __shfl(kt, i3);
                    // 4 row-gathers in flight before any use
                    unsigned xv0 = *(const unsigned*)(xkj + (size_t)k0 * 128 + lane * 2);
                    unsigned xv1 = *(const unsigned*)(xkj + (size_t)k1 * 128 + lane * 2);
                    unsigned xv2 = *(const unsigned*)(xkj + (size_t)k2 * 128 + lane * 2);
                    unsigned xv3 = *(const unsigned*)(xkj + (size_t)k3 * 128 + lane * 2);
                    unsigned xq[4] = {xv0, xv1, xv2, xv3};
                    #pragma unroll
                    for (int s = 0; s < 4; ++s) {
                        if (s < m4) {
                            float x0 = bf2f((short)(xq[s] & 0xffff));
                            float x1 = bf2f((short)(xq[s] >> 16));
                            const float* sp = sbfhp + (size_t)(p0 + tc + tb + s) * 8;
                            #pragma unroll
                            for (int j = 0; j < 8; ++j) {
                                float sv = sp[j];
                                accA[j] += sv * x0; accB[j] += sv * x1;
                            }
                        }
                    }
                }
            }
        }
        unsigned xr = (unsigned)((e_loc & 7) << 4);
        #pragma unroll
        for (int j = 0; j < 8; ++j) {
            unsigned bo = ((unsigned)(e_loc * 2048 + (j * 256 + lane * 4))) ^ xr;
            unsigned pk = (unsigned)(unsigned short)f2bf(accA[j]) |
                          ((unsigned)(unsigned short)f2bf(accB[j]) << 16);
            *(unsigned*)((char*)ylds + bo) = pk;
        }
    }

    // ---- GEMM phase: [32,1024] @ [1024,128], 8 waves = 2 row-tiles x 4 col-quarters ----
    int rt = wv >> 2, cq = wv & 3;
    f32x4 acc0 = (f32x4){0.f,0.f,0.f,0.f}, acc1 = (f32x4){0.f,0.f,0.f,0.f};

    // reg-prefetch WbT chunk 0 (each thread 2 x 16B)
    short8 wreg0, wreg1;
    {
        int u0 = tid, u1 = tid + 512;
        wreg0 = *(const short8*)(WbT + (size_t)(u0 >> 3) * 1024 + (u0 & 7) * 8);
        wreg1 = *(const short8*)(WbT + (size_t)(u1 >> 3) * 1024 + (u1 & 7) * 8);
    }

    for (int c = 0; c < 16; ++c) {     // K chunks of 64
        __syncthreads();               // c=0: build writes visible; else: prev reads done
        {
            int u0 = tid, u1 = tid + 512;
            int bi0 = u0 >> 3, bc0 = u0 & 7;
            int bi1 = u1 >> 3, bc1 = u1 & 7;
            unsigned bo0 = (unsigned)(bi0 * 128 + bc0 * 16) ^ (unsigned)((bi0 & 7) << 4);
            unsigned bo1 = (unsigned)(bi1 * 128 + bc1 * 16) ^ (unsigned)((bi1 & 7) << 4);
            *(short8*)((char*)blds + bo0) = wreg0;
            *(short8*)((char*)blds + bo1) = wreg1;
            if (c < 15) {
                wreg0 = *(const short8*)(WbT + (size_t)bi0 * 1024 + (c + 1) * 64 + bc0 * 8);
                wreg1 = *(const short8*)(WbT + (size_t)bi1 * 1024 + (c + 1) * 64 + bc1 * 8);
            }
        }
        __syncthreads();
        #pragma unroll
        for (int kk = 0; kk < 2; ++kk) {
            int row = rt * 16 + ln;
            unsigned ab = ((unsigned)(row * 2048 + (c * 64 + kk * 32 + g * 8) * 2))
                          ^ ((unsigned)((row & 7) << 4));
            short8 a = *(short8*)((char*)ylds + ab);
            #pragma unroll
            for (int nt = 0; nt < 2; ++nt) {
                int bi = cq * 32 + nt * 16 + ln;
                unsigned bb = ((unsigned)(bi * 128 + kk * 64 + g * 16))
                              ^ ((unsigned)((bi & 7) << 4));
                short8 b = *(short8*)((char*)blds + bb);
                if (nt == 0) acc0 = __builtin_amdgcn_mfma_f32_16x16x32_bf16(a, b, acc0, 0, 0, 0);
                else         acc1 = __builtin_amdgcn_mfma_f32_16x16x32_bf16(a, b, acc1, 0, 0, 0);
            }
        }
    }

    // epilogue: h = xji + acc, hb = bf16(h)
    #pragma unroll
    for (int nt = 0; nt < 2; ++nt) {
        int col = cq * 32 + nt * 16 + ln;
        #pragma unroll
        for (int r2 = 0; r2 < 4; ++r2) {
            int e = e0 + rt * 16 + g * 4 + r2;   // C/D: row=(lane>>4)*4+reg, col=lane&15
            if (e < NEDGE) {
                size_t o = (size_t)e * 128 + col;
                float v = (nt == 0 ? acc0[r2] : acc1[r2]) + xji[o];
                h[o] = v; hb[o] = f2bf(v);
            }
        }
    }
}

// ---------- fused x_ji / x_kj: both 128x128 GEMMs on A=xb ----------
__global__ __launch_bounds__(256) void gemm_x(
    const short* __restrict__ xb, const short* __restrict__ Wjit,
    const short* __restrict__ Wkjt, const float* __restrict__ bji,
    const float* __restrict__ bkj, const float* __restrict__ rbf,
    const float* __restrict__ Wrbf, float* __restrict__ xji,
    short* __restrict__ xkj)
{
    __shared__ __align__(16) short w1[128 * 128];
    __shared__ __align__(16) short w2[128 * 128];
    int tid = threadIdx.x;
    int wv = tid >> 6, lane = tid & 63, g = lane >> 4, ln = lane & 15;
    int rowBase = blockIdx.x * 64 + wv * 16;

    #pragma unroll
    for (int q = 0; q < 8; ++q) {
        int idx = tid + q * 256;
        int wi = idx >> 4, wc = idx & 15;
        unsigned bo = (unsigned)(wi * 256 + wc * 16) ^ (unsigned)((wi & 7) << 4);
        *(short8*)((char*)w1 + bo) = *(const short8*)(Wjit + wi * 128 + wc * 8);
        *(short8*)((char*)w2 + bo) = *(const short8*)(Wkjt + wi * 128 + wc * 8);
    }

    int arow = rowBase + ln; if (arow > NEDGE - 1) arow = NEDGE - 1;
    const short8* Ar = (const short8*)(xb + (size_t)arow * 128);
    short8 af[4];
    #pragma unroll
    for (int kc = 0; kc < 4; ++kc) af[kc] = Ar[kc * 4 + g];

    __syncthreads();

    f32x4 acc1[8], acc2[8];
    #pragma unroll
    for (int nt = 0; nt < 8; ++nt) {
        acc1[nt] = (f32x4){0.f,0.f,0.f,0.f};
        acc2[nt] = (f32x4){0.f,0.f,0.f,0.f};
    }
    #pragma unroll
    for (int kc = 0; kc < 4; ++kc) {
        #pragma unroll
        for (int nt = 0; nt < 8; ++nt) {
            int wi = nt * 16 + ln;
            unsigned bo = (unsigned)(wi * 256 + kc * 64 + g * 16) ^ (unsigned)((wi & 7) << 4);
            short8 b1 = *(short8*)((char*)w1 + bo);
            short8 b2 = *(short8*)((char*)w2 + bo);
            acc1[nt] = __builtin_amdgcn_mfma_f32_16x16x32_bf16(af[kc], b1, acc1[nt], 0, 0, 0);
            acc2[nt] = __builtin_amdgcn_mfma_f32_16x16x32_bf16(af[kc], b2, acc2[nt], 0, 0, 0);
        }
    }

    #pragma unroll
    for (int r = 0; r < 4; ++r) {
        int row = rowBase + g * 4 + r;
        bool ok = row < NEDGE;
        int crow = ok ? row : NEDGE - 1;
        float rr[6];
        #pragma unroll
        for (int q = 0; q < 6; ++q) rr[q] = rbf[(size_t)crow * 6 + q];
        #pragma unroll
        for (int nt = 0; nt < 8; ++nt) {
            int col = nt * 16 + ln;
            if (ok) {
                size_t o = (size_t)row * 128 + col;
                xji[o] = silu_f(acc1[nt][r] + bji[col]);
                float rb = 0.f;
                #pragma unroll
                for (int q = 0; q < 6; ++q) rb += rr[q] * Wrbf[q * 128 + col];
                xkj[o] = f2bf(silu_f(acc2[nt][r] + bkj[col]) * rb);
            }
        }
    }
}

// ---------- fused residual chain: 8 layers, h-tile in registers ----------
// modes: 0 = t = silu(acc+b) -> act; 1 = h += silu(acc+b) -> act;
//        2 = h = silu(acc+b) + x -> act; 3 = out = silu(acc+b) (f32 store)
struct ChainP { const short* W[8]; const float* B[8]; };
__global__ __launch_bounds__(256) void chain_kernel(
    ChainP p, const short* __restrict__ hb, const float* __restrict__ hin,
    const float* __restrict__ x, float* __restrict__ out)
{
    __shared__ __align__(16) short wlds[2][128 * 128];  // 64 KB double-buffered weights
    __shared__ __align__(16) short actlds[64 * 128];    // 16 KB activation tile
    int tid = threadIdx.x;
    int wv = tid >> 6, lane = tid & 63, g = lane >> 4, ln = lane & 15;
    int rowBase = blockIdx.x * 64;

    // stage W0 -> wlds[0]
    #pragma unroll
    for (int q = 0; q < 8; ++q) {
        int idx = tid + q * 256;
        int wi = idx >> 4, wc = idx & 15;
        unsigned bo = (unsigned)(wi * 256 + wc * 16) ^ (unsigned)((wi & 7) << 4);
        *(short8*)((char*)wlds[0] + bo) = *(const short8*)(p.W[0] + wi * 128 + wc * 8);
    }

    // h tile in C-layout registers
    float hreg[8][4];
    #pragma unroll
    for (int nt = 0; nt < 8; ++nt)
        #pragma unroll
        for (int r = 0; r < 4; ++r) {
            int row = rowBase + wv * 16 + g * 4 + r;
            if (row > NEDGE - 1) row = NEDGE - 1;
            hreg[nt][r] = hin[(size_t)row * 128 + nt * 16 + ln];
        }

    // layer-0 A-frags from global hb
    int arow = rowBase + wv * 16 + ln; if (arow > NEDGE - 1) arow = NEDGE - 1;
    short8 af[4];
    #pragma unroll
    for (int kc = 0; kc < 4; ++kc)
        af[kc] = *(const short8*)(hb + (size_t)arow * 128 + kc * 32 + g * 8);

    const int modes[8] = {0, 1, 2, 0, 1, 0, 1, 3};

    #pragma unroll
    for (int l = 0; l < 8; ++l) {
        __syncthreads();                 // wlds[l&1] + actlds ready
        if (l > 0) {
            int ar = wv * 16 + ln;
            unsigned sw = ((unsigned)(ar & 7)) << 4;
            #pragma unroll
            for (int kc = 0; kc < 4; ++kc)
                af[kc] = *(short8*)((char*)actlds +
                          (((unsigned)(ar * 256 + (kc * 32 + g * 8) * 2)) ^ sw));
        }
        __syncthreads();                 // all af reads issued before act rewrite

        f32x4 acc[8];
        #pragma unroll
        for (int nt = 0; nt < 8; ++nt) acc[nt] = (f32x4){0.f,0.f,0.f,0.f};
        #pragma unroll
        for (int kc = 0; kc < 4; ++kc) {
            #pragma unroll
            for (int nt = 0; nt < 8; ++nt) {
                int wi = nt * 16 + ln;
                unsigned bo = (unsigned)(wi * 256 + kc * 64 + g * 16) ^ (unsigned)((wi & 7) << 4);
                short8 b = *(short8*)((char*)wlds[l & 1] + bo);
                acc[nt] = __builtin_amdgcn_mfma_f32_16x16x32_bf16(af[kc], b, acc[nt], 0, 0, 0);
            }
        }

        if (l < 7) {                     // stage next weight into the other buffer
            #pragma unroll
            for (int q = 0; q < 8; ++q) {
                int idx = tid + q * 256;
                int wi = idx >> 4, wc = idx & 15;
                unsigned bo = (unsigned)(wi * 256 + wc * 16) ^ (unsigned)((wi & 7) << 4);
                *(short8*)((char*)wlds[(l + 1) & 1] + bo) =
                    *(const short8*)(p.W[l + 1] + wi * 128 + wc * 8);
            }
        }

        int mode = modes[l];
        #pragma unroll
        for (int nt = 0; nt < 8; ++nt) {
            int col = nt * 16 + ln;
            float bv = p.B[l][col];
            #pragma unroll
            for (int r = 0; r < 4; ++r) {
                int lrow = wv * 16 + g * 4 + r;
                int row = rowBase + lrow;
                float v = silu_f(acc[nt][r] + bv);
                if (mode == 1) { v += hreg[nt][r]; hreg[nt][r] = v; }
                else if (mode == 2) {
                    int cr = row > NEDGE - 1 ? NEDGE - 1 : row;
                    v += x[(size_t)cr * 128 + col];
                    hreg[nt][r] = v;
                } else if (mode == 3) {
                    if (row < NEDGE) out[(size_t)row * 128 + col] = v;
                }
                if (mode != 3) {
                    unsigned sw2 = ((unsigned)(lrow & 7)) << 4;
                    unsigned bo = ((unsigned)(lrow * 256 + col * 2)) ^ sw2;
                    *(short*)((char*)actlds + bo) = f2bf(v);
                }
            }
        }
    }
}

// ---------- launch ----------
extern "C" void kernel_launch(void* const* d_in, const int* in_sizes, int n_in,
                              void* d_out, int out_size, void* d_ws, size_t ws_size,
                              hipStream_t stream) {
    const float* x      = (const float*)d_in[0];
    const float* rbf    = (const float*)d_in[1];
    const float* sbf    = (const float*)d_in[2];
    const int*   idx_kj = (const int*)d_in[3];
    const int*   idx_ji = (const int*)d_in[4];
    const float* W_rbf  = (const float*)d_in[5];
    const float* W_sbf  = (const float*)d_in[6];
    const float* Wkj    = (const float*)d_in[7];
    const float* bkj    = (const float*)d_in[8];
    const float* Wji    = (const float*)d_in[9];
    const float* bji    = (const float*)d_in[10];
    const float* Wbil   = (const float*)d_in[11];
    const float* bW1    = (const float*)d_in[12];
    const float* bb1    = (const float*)d_in[13];
    const float* bW2    = (const float*)d_in[14];
    const float* bb2    = (const float*)d_in[15];
    const float* Wlin   = (const float*)d_in[16];
    const float* blin   = (const float*)d_in[17];
    const float* aW1    = (const float*)d_in[18];
    const float* ab1    = (const float*)d_in[19];
    const float* aW2    = (const float*)d_in[20];
    const float* ab2    = (const float*)d_in[21];
    const float* Wout   = (const float*)d_in[22];
    const float* bout   = (const float*)d_in[23];
    float* out = (float*)d_out;

    char* ws = (char*)d_ws;
    size_t off = 0;
    auto alloc = [&](size_t bytes) { char* p = ws + off; off += bytes; return p; };
    short* xb    = (short*)alloc((size_t)NEDGE * 128 * 2);
    short* xkj   = (short*)alloc((size_t)NEDGE * 128 * 2);
    short* hbb   = (short*)alloc((size_t)NEDGE * 128 * 2);
    float* sbfh  = (float*)alloc((size_t)NTRI * 8 * 4);
    float* sbfhp = (float*)alloc(((size_t)NTRI * 8 + 64) * 4);
    float* xji   = (float*)alloc((size_t)NEDGE * 128 * 4);
    float* h     = (float*)alloc((size_t)NEDGE * 128 * 4);
    short* WbT   = (short*)alloc((size_t)131072 * 2);
    short* Wt[10];
    for (int i = 0; i < 10; ++i) Wt[i] = (short*)alloc((size_t)16384 * 2);
    int* counts  = (int*)alloc((size_t)NEDGE * 4);
    int* partial = (int*)alloc((size_t)NEDGE * 4);
    int* rowptr  = (int*)alloc((size_t)NEDGE * 4);
    int* wcur    = (int*)alloc((size_t)NEDGE * 4);
    int* bsum    = (int*)alloc(256 * 4);
    int* perm    = (int*)alloc((size_t)NTRI * 4);
    int* kjp     = (int*)alloc((size_t)(NTRI + 64) * 4);
    (void)ws_size; (void)n_in; (void)in_sizes; (void)out_size;

    hipMemsetAsync(counts, 0, (size_t)NEDGE * 4, stream);

    cvt_kernel<<<dim3((NEDGE * 128 / 4 + 255) / 256), 256, 0, stream>>>(x, xb, NEDGE * 128 / 4);
    cvt_kernel<<<dim3((131072 / 4 + 255) / 256), 256, 0, stream>>>(Wbil, WbT, 131072 / 4);

    TP tp;
    const float* srcs[10] = {Wkj, Wji, bW1, bW2, Wlin, aW1, aW1 + 16384, aW2, aW2 + 16384, Wout};
    for (int i = 0; i < 10; ++i) { tp.s[i] = srcs[i]; tp.d[i] = Wt[i]; }
    t128_all<<<dim3(64, 10), 256, 0, stream>>>(tp);

    sbfh_kernel<<<dim3(NTRI / 32), 256, 0, stream>>>(sbf, W_sbf, sbfh);

    // CSR of idx_ji
    int NB1 = (NEDGE + 255) / 256;   // 196
    hist_kernel<<<dim3((NTRI + 255) / 256), 256, 0, stream>>>(idx_ji, counts);
    scan1_kernel<<<dim3(NB1), 256, 0, stream>>>(counts, partial, bsum);
    scan2_kernel<<<dim3(1), 256, 0, stream>>>(bsum, NB1);
    scan3_kernel<<<dim3(NB1), 256, 0, stream>>>(partial, bsum, rowptr, wcur);
    scatter_kernel<<<dim3((NTRI + 255) / 256), 256, 0, stream>>>(idx_ji, wcur, perm);
    permute_kernel<<<dim3((NTRI + 255) / 256), 256, 0, stream>>>(perm, idx_kj, sbfh, kjp, sbfhp);

    int gE = (NEDGE + 63) / 64;   // 782
    // x_ji = silu(x@Wji+bji) f32 ; x_kj = silu(x@Wkj+bkj)*(rbf@W_rbf) bf16
    gemm_x<<<gE, 256, 0, stream>>>(xb, Wt[1], Wt[0], bji, bkj, rbf, W_rbf, xji, xkj);

    // fused bilinear + segment-sum: h = xji + (y @ Wbil), hb = bf16(h)
    bilinear_fused<<<dim3((NEDGE + BE - 1) / BE), 512, 0, stream>>>(
        xkj, sbfhp, kjp, rowptr, counts, xji, WbT, h, hbb);

    // fused 8-layer residual chain -> out
    ChainP cp;
    cp.W[0] = Wt[2]; cp.B[0] = bb1;
    cp.W[1] = Wt[3]; cp.B[1] = bb2;
    cp.W[2] = Wt[4]; cp.B[2] = blin;
    cp.W[3] = Wt[5]; cp.B[3] = ab1;
    cp.W[4] = Wt[7]; cp.B[4] = ab2;
    cp.W[5] = Wt[6]; cp.B[5] = ab1 + 128;
    cp.W[6] = Wt[8]; cp.B[6] = ab2 + 128;
    cp.W[7] = Wt[9]; cp.B[7] = bout;
    chain_kernel<<<gE, 256, 0, stream>>>(cp, hbb, h, x, out);
}

// Round 6
// 352.160 us; speedup vs baseline: 2.0196x; 1.0157x over previous
//
#include <hip/hip_runtime.h>
#include <hip/hip_bf16.h>

// DimeNet InteractionBlock for MI355X (gfx950).
#define NEDGE 50000
#define NTRI 200000

typedef __attribute__((ext_vector_type(8))) short short8;   // 8 bf16 (4 VGPRs) — MFMA A/B frag
typedef __attribute__((ext_vector_type(4))) short short4v;
typedef __attribute__((ext_vector_type(4))) float f32x4;    // MFMA C/D frag

__device__ __forceinline__ float silu_f(float v) { return v / (1.0f + __expf(-v)); }

// f32 -> bf16 bits, round-to-nearest-even
__device__ __forceinline__ short f2bf(float f) {
    unsigned u = __float_as_uint(f);
    unsigned r = (u + 0x7FFFu + ((u >> 16) & 1u)) >> 16;
    return (short)r;
}
__device__ __forceinline__ float bf2f(short s) {
    return __uint_as_float(((unsigned)(unsigned short)s) << 16);
}

// ---------- prep kernels ----------

__global__ void cvt_kernel(const float* __restrict__ src, short* __restrict__ dst, int n4) {
    int i = blockIdx.x * 256 + threadIdx.x;
    if (i < n4) {
        float4 v = ((const float4*)src)[i];
        short4v o;
        o[0] = f2bf(v.x); o[1] = f2bf(v.y); o[2] = f2bf(v.z); o[3] = f2bf(v.w);
        ((short4v*)dst)[i] = o;
    }
}

// 10x 128x128 transpose+convert: dst[n*128+k] = bf16(src[k*128+n])
struct TP { const float* s[10]; short* d[10]; };
__global__ void t128_all(TP p) {
    const float* __restrict__ src = p.s[blockIdx.y];
    short* __restrict__ dst = p.d[blockIdx.y];
    int i = blockIdx.x * 256 + threadIdx.x;    // grid.x = 64 -> 16384 exactly
    int k = i >> 7, n = i & 127;
    dst[n * 128 + k] = f2bf(src[i]);
}

// sbf_h = sbf @ W_sbf : [T,42]@[42,8] -> f32 [T,8]; 32 rows/block, LDS-staged
__global__ __launch_bounds__(256) void sbfh_kernel(const float* __restrict__ sbf,
                                                   const float* __restrict__ Wsbf,
                                                   float* __restrict__ out) {
    __shared__ float s[32 * 42];
    __shared__ float w[42 * 8];
    int tid = threadIdx.x;
    size_t base = (size_t)blockIdx.x * 32;          // 200000/32 = 6250 exact
    for (int u = tid; u < 32 * 42; u += 256) s[u] = sbf[base * 42 + u];
    for (int u = tid; u < 42 * 8; u += 256) w[u] = Wsbf[u];
    __syncthreads();
    int row = tid >> 3, j = tid & 7;
    float acc = 0.f;
    #pragma unroll
    for (int k = 0; k < 42; ++k) acc += s[row * 42 + k] * w[k * 8 + j];
    out[base * 8 + tid] = acc;
}

// ---------- CSR build for idx_ji ----------

__global__ void hist_kernel(const int* __restrict__ ji, int* __restrict__ counts) {
    int i = blockIdx.x * 256 + threadIdx.x;
    if (i < NTRI) atomicAdd(&counts[ji[i]], 1);
}

__global__ void scan1_kernel(const int* __restrict__ counts, int* __restrict__ partial,
                             int* __restrict__ bsum) {
    __shared__ int tmp[256];
    int tid = threadIdx.x;
    int i = blockIdx.x * 256 + tid;
    int v = (i < NEDGE) ? counts[i] : 0;
    tmp[tid] = v; __syncthreads();
    #pragma unroll
    for (int o = 1; o < 256; o <<= 1) {
        int t = (tid >= o) ? tmp[tid - o] : 0;
        __syncthreads();
        tmp[tid] += t;
        __syncthreads();
    }
    if (i < NEDGE) partial[i] = tmp[tid] - v;
    if (tid == 255) bsum[blockIdx.x] = tmp[255];
}

__global__ void scan2_kernel(int* __restrict__ bsum, int nb) {
    __shared__ int tmp[256];
    int tid = threadIdx.x;
    int v = (tid < nb) ? bsum[tid] : 0;
    tmp[tid] = v; __syncthreads();
    #pragma unroll
    for (int o = 1; o < 256; o <<= 1) {
        int t = (tid >= o) ? tmp[tid - o] : 0;
        __syncthreads();
        tmp[tid] += t;
        __syncthreads();
    }
    if (tid < nb) bsum[tid] = tmp[tid] - v;
}

__global__ void scan3_kernel(const int* __restrict__ partial, const int* __restrict__ bsum,
                             int* __restrict__ rowptr, int* __restrict__ wcur) {
    int i = blockIdx.x * 256 + threadIdx.x;
    if (i < NEDGE) {
        int r = partial[i] + bsum[blockIdx.x];
        rowptr[i] = r;
        wcur[i] = r;
    }
}

// scatter + payload permute fused: kjp[p] = idx_kj[w], sbfhp[p] = sbfh[w]
__global__ void scatter_kernel(const int* __restrict__ ji, const int* __restrict__ idx_kj,
                               const float* __restrict__ sbfh, int* __restrict__ wcur,
                               int* __restrict__ kjp, float* __restrict__ sbfhp) {
    int w = blockIdx.x * 256 + threadIdx.x;
    if (w < NTRI) {
        int p = atomicAdd(&wcur[ji[w]], 1);
        kjp[p] = idx_kj[w];
        float4 a = *(const float4*)(sbfh + (size_t)w * 8);
        float4 b = *(const float4*)(sbfh + (size_t)w * 8 + 4);
        *(float4*)(sbfhp + (size_t)p * 8) = a;
        *(float4*)(sbfhp + (size_t)p * 8 + 4) = b;
    }
}

// ---------- fused bilinear: build 32-edge y-tile in LDS, GEMM vs WbT, h = xji + acc ----------
#define BE 32
__global__ __launch_bounds__(512) void bilinear_fused(
    const short* __restrict__ xkj, const float* __restrict__ sbfhp,
    const int* __restrict__ kjp, const int* __restrict__ rowptr,
    const int* __restrict__ counts,
    const float* __restrict__ xji, const short* __restrict__ WbT,
    float* __restrict__ h, short* __restrict__ hb)
{
    __shared__ __align__(16) short ylds[BE * 1024];  // 64 KB, XOR-swizzled rows (2048B)
    __shared__ __align__(16) short blds[128 * 64];   // 16 KB WbT k-chunk, swizzled (128B rows)

    int tid = threadIdx.x;
    int e0 = blockIdx.x * BE;
    int wv = tid >> 6, lane = tid & 63, g = lane >> 4, ln = lane & 15;

    // per-wave: fetch the block's 32 (p0, n) pairs coalesced, then shfl
    int eidx = e0 + ((lane < BE) ? lane : BE - 1);
    if (eidx > NEDGE - 1) eidx = NEDGE - 1;
    int rp_l = rowptr[eidx];
    int ct_l = counts[eidx];

    // ---- build phase: wave wv builds edges wv*4 .. wv*4+4 ----
    for (int es = 0; es < 4; ++es) {
        int e_loc = wv * 4 + es;
        int e = e0 + e_loc;
        float accA[8], accB[8];
        #pragma unroll
        for (int j = 0; j < 8; ++j) { accA[j] = 0.f; accB[j] = 0.f; }
        if (e < NEDGE) {
            int p0 = __builtin_amdgcn_readfirstlane(__shfl(rp_l, e_loc));
            int n  = __builtin_amdgcn_readfirstlane(__shfl(ct_l, e_loc));
            for (int tc = 0; tc < n; tc += 64) {
                int mm = n - tc; if (mm > 64) mm = 64;
                int li = (lane < mm) ? lane : mm - 1;
                int kt = kjp[p0 + tc + li];              // one coalesced load
                for (int tb = 0; tb < mm; tb += 4) {
                    int m4 = mm - tb; if (m4 > 4) m4 = 4;
                    int i1 = tb + 1 < mm ? tb + 1 : mm - 1;
                    int i2 = tb + 2 < mm ? tb + 2 : mm - 1;
                    int i3 = tb + 3 < mm ? tb + 3 : mm - 1;
                    int k0 = __shfl(kt, tb), k1 = __shfl(kt, i1);
                    int k2 = __shfl(kt, i2), k3 = __shfl(kt, i3);
                    // 4 row-gathers in flight before any use
                    unsigned xv0 = *(const unsigned*)(xkj + (size_t)k0 * 128 + lane * 2);
                    unsigned xv1 = *(const unsigned*)(xkj + (size_t)k1 * 128 + lane * 2);
                    unsigned xv2 = *(const unsigned*)(xkj + (size_t)k2 * 128 + lane * 2);
                    unsigned xv3 = *(const unsigned*)(xkj + (size_t)k3 * 128 + lane * 2);
                    unsigned xq[4] = {xv0, xv1, xv2, xv3};
                    #pragma unroll
                    for (int s = 0; s < 4; ++s) {
                        if (s < m4) {
                            float x0 = bf2f((short)(xq[s] & 0xffff));
                            float x1 = bf2f((short)(xq[s] >> 16));
                            const float* sp = sbfhp + (size_t)(p0 + tc + tb + s) * 8;
                            #pragma unroll
                            for (int j = 0; j < 8; ++j) {
                                float sv = sp[j];
                                accA[j] += sv * x0; accB[j] += sv * x1;
                            }
                        }
                    }
                }
            }
        }
        unsigned xr = (unsigned)((e_loc & 7) << 4);
        #pragma unroll
        for (int j = 0; j < 8; ++j) {
            unsigned bo = ((unsigned)(e_loc * 2048 + (j * 256 + lane * 4))) ^ xr;
            unsigned pk = (unsigned)(unsigned short)f2bf(accA[j]) |
                          ((unsigned)(unsigned short)f2bf(accB[j]) << 16);
            *(unsigned*)((char*)ylds + bo) = pk;
        }
    }

    // ---- GEMM phase: [32,1024] @ [1024,128], 8 waves = 2 row-tiles x 4 col-quarters ----
    int rt = wv >> 2, cq = wv & 3;
    f32x4 acc0 = (f32x4){0.f,0.f,0.f,0.f}, acc1 = (f32x4){0.f,0.f,0.f,0.f};

    // reg-prefetch WbT chunk 0 (each thread 2 x 16B)
    short8 wreg0, wreg1;
    {
        int u0 = tid, u1 = tid + 512;
        wreg0 = *(const short8*)(WbT + (size_t)(u0 >> 3) * 1024 + (u0 & 7) * 8);
        wreg1 = *(const short8*)(WbT + (size_t)(u1 >> 3) * 1024 + (u1 & 7) * 8);
    }

    for (int c = 0; c < 16; ++c) {     // K chunks of 64
        __syncthreads();               // c=0: build writes visible; else: prev reads done
        {
            int u0 = tid, u1 = tid + 512;
            int bi0 = u0 >> 3, bc0 = u0 & 7;
            int bi1 = u1 >> 3, bc1 = u1 & 7;
            unsigned bo0 = (unsigned)(bi0 * 128 + bc0 * 16) ^ (unsigned)((bi0 & 7) << 4);
            unsigned bo1 = (unsigned)(bi1 * 128 + bc1 * 16) ^ (unsigned)((bi1 & 7) << 4);
            *(short8*)((char*)blds + bo0) = wreg0;
            *(short8*)((char*)blds + bo1) = wreg1;
            if (c < 15) {
                wreg0 = *(const short8*)(WbT + (size_t)bi0 * 1024 + (c + 1) * 64 + bc0 * 8);
                wreg1 = *(const short8*)(WbT + (size_t)bi1 * 1024 + (c + 1) * 64 + bc1 * 8);
            }
        }
        __syncthreads();
        #pragma unroll
        for (int kk = 0; kk < 2; ++kk) {
            int row = rt * 16 + ln;
            unsigned ab = ((unsigned)(row * 2048 + (c * 64 + kk * 32 + g * 8) * 2))
                          ^ ((unsigned)((row & 7) << 4));
            short8 a = *(short8*)((char*)ylds + ab);
            #pragma unroll
            for (int nt = 0; nt < 2; ++nt) {
                int bi = cq * 32 + nt * 16 + ln;
                unsigned bb = ((unsigned)(bi * 128 + kk * 64 + g * 16))
                              ^ ((unsigned)((bi & 7) << 4));
                short8 b = *(short8*)((char*)blds + bb);
                if (nt == 0) acc0 = __builtin_amdgcn_mfma_f32_16x16x32_bf16(a, b, acc0, 0, 0, 0);
                else         acc1 = __builtin_amdgcn_mfma_f32_16x16x32_bf16(a, b, acc1, 0, 0, 0);
            }
        }
    }

    // epilogue: h = xji + acc, hb = bf16(h)
    #pragma unroll
    for (int nt = 0; nt < 2; ++nt) {
        int col = cq * 32 + nt * 16 + ln;
        #pragma unroll
        for (int r2 = 0; r2 < 4; ++r2) {
            int e = e0 + rt * 16 + g * 4 + r2;   // C/D: row=(lane>>4)*4+reg, col=lane&15
            if (e < NEDGE) {
                size_t o = (size_t)e * 128 + col;
                float v = (nt == 0 ? acc0[r2] : acc1[r2]) + xji[o];
                h[o] = v; hb[o] = f2bf(v);
            }
        }
    }
}

// ---------- fused x_ji / x_kj: both 128x128 GEMMs on A=xb ----------
__global__ __launch_bounds__(256) void gemm_x(
    const short* __restrict__ xb, const short* __restrict__ Wjit,
    const short* __restrict__ Wkjt, const float* __restrict__ bji,
    const float* __restrict__ bkj, const float* __restrict__ rbf,
    const float* __restrict__ Wrbf, float* __restrict__ xji,
    short* __restrict__ xkj)
{
    __shared__ __align__(16) short w1[128 * 128];
    __shared__ __align__(16) short w2[128 * 128];
    int tid = threadIdx.x;
    int wv = tid >> 6, lane = tid & 63, g = lane >> 4, ln = lane & 15;
    int rowBase = blockIdx.x * 64 + wv * 16;

    #pragma unroll
    for (int q = 0; q < 8; ++q) {
        int idx = tid + q * 256;
        int wi = idx >> 4, wc = idx & 15;
        unsigned bo = (unsigned)(wi * 256 + wc * 16) ^ (unsigned)((wi & 7) << 4);
        *(short8*)((char*)w1 + bo) = *(const short8*)(Wjit + wi * 128 + wc * 8);
        *(short8*)((char*)w2 + bo) = *(const short8*)(Wkjt + wi * 128 + wc * 8);
    }

    int arow = rowBase + ln; if (arow > NEDGE - 1) arow = NEDGE - 1;
    const short8* Ar = (const short8*)(xb + (size_t)arow * 128);
    short8 af[4];
    #pragma unroll
    for (int kc = 0; kc < 4; ++kc) af[kc] = Ar[kc * 4 + g];

    __syncthreads();

    f32x4 acc1[8], acc2[8];
    #pragma unroll
    for (int nt = 0; nt < 8; ++nt) {
        acc1[nt] = (f32x4){0.f,0.f,0.f,0.f};
        acc2[nt] = (f32x4){0.f,0.f,0.f,0.f};
    }
    #pragma unroll
    for (int kc = 0; kc < 4; ++kc) {
        #pragma unroll
        for (int nt = 0; nt < 8; ++nt) {
            int wi = nt * 16 + ln;
            unsigned bo = (unsigned)(wi * 256 + kc * 64 + g * 16) ^ (unsigned)((wi & 7) << 4);
            short8 b1 = *(short8*)((char*)w1 + bo);
            short8 b2 = *(short8*)((char*)w2 + bo);
            acc1[nt] = __builtin_amdgcn_mfma_f32_16x16x32_bf16(af[kc], b1, acc1[nt], 0, 0, 0);
            acc2[nt] = __builtin_amdgcn_mfma_f32_16x16x32_bf16(af[kc], b2, acc2[nt], 0, 0, 0);
        }
    }

    #pragma unroll
    for (int r = 0; r < 4; ++r) {
        int row = rowBase + g * 4 + r;
        bool ok = row < NEDGE;
        int crow = ok ? row : NEDGE - 1;
        float rr[6];
        #pragma unroll
        for (int q = 0; q < 6; ++q) rr[q] = rbf[(size_t)crow * 6 + q];
        #pragma unroll
        for (int nt = 0; nt < 8; ++nt) {
            int col = nt * 16 + ln;
            if (ok) {
                size_t o = (size_t)row * 128 + col;
                xji[o] = silu_f(acc1[nt][r] + bji[col]);
                float rb = 0.f;
                #pragma unroll
                for (int q = 0; q < 6; ++q) rb += rr[q] * Wrbf[q * 128 + col];
                xkj[o] = f2bf(silu_f(acc2[nt][r] + bkj[col]) * rb);
            }
        }
    }
}

// ---------- fused residual chain: 8 layers, h-tile in registers ----------
// 512 thr = 8 waves: wave = (rt 0..3, ch 0..1); 64 rows/block, 4 nt per wave.
// Single 32KB W buffer + reg prefetch; act tile 16KB; conflict-free packed b32 act stores.
// modes: 0 = t = silu(acc) -> act; 1 = h += silu(acc) -> act;
//        2 = h = silu(acc) + x -> act; 3 = out = silu(acc) (f32 store)
struct ChainP { const short* W[8]; const float* B[8]; };
__global__ __launch_bounds__(512, 4) void chain_kernel(
    ChainP p, const short* __restrict__ hb, const float* __restrict__ hin,
    const float* __restrict__ x, float* __restrict__ out)
{
    __shared__ __align__(16) short wlds[128 * 128];   // 32 KB, swizzled
    __shared__ __align__(16) short actlds[64 * 128];  // 16 KB, swizzled
    int tid = threadIdx.x;
    int wv = tid >> 6, lane = tid & 63, g = lane >> 4, ln = lane & 15;
    int rt = wv >> 1, ch = wv & 1;
    int rowBase = blockIdx.x * 64;

    // stage W0 (each thread 4 x 16B)
    #pragma unroll
    for (int q = 0; q < 4; ++q) {
        int idx = tid + q * 512;
        int wi = idx >> 4, wc = idx & 15;
        unsigned bo = (unsigned)(wi * 256 + wc * 16) ^ (unsigned)((wi & 7) << 4);
        *(short8*)((char*)wlds + bo) = *(const short8*)(p.W[0] + wi * 128 + wc * 8);
    }

    // h tile in C-layout registers: rows rt*16+g*4+r, cols ch*64+nt*16+ln
    float hreg[4][4];
    #pragma unroll
    for (int nt = 0; nt < 4; ++nt)
        #pragma unroll
        for (int r = 0; r < 4; ++r) {
            int row = rowBase + rt * 16 + g * 4 + r;
            if (row > NEDGE - 1) row = NEDGE - 1;
            hreg[nt][r] = hin[(size_t)row * 128 + ch * 64 + nt * 16 + ln];
        }

    // layer-0 A-frags from global hb
    int arow = rowBase + rt * 16 + ln; if (arow > NEDGE - 1) arow = NEDGE - 1;
    short8 af[4];
    #pragma unroll
    for (int kc = 0; kc < 4; ++kc)
        af[kc] = *(const short8*)(hb + (size_t)arow * 128 + kc * 32 + g * 8);

    short8 wreg[4];
    const int modes[8] = {0, 1, 2, 0, 1, 0, 1, 3};

    #pragma unroll
    for (int l = 0; l < 8; ++l) {
        __syncthreads();                 // B1: act(l-1) written; W[l] MFMA reads of l-1 done
        if (l > 0) {
            #pragma unroll
            for (int q = 0; q < 4; ++q) {   // W[l] reg -> LDS
                int idx = tid + q * 512;
                int wi = idx >> 4, wc = idx & 15;
                unsigned bo = (unsigned)(wi * 256 + wc * 16) ^ (unsigned)((wi & 7) << 4);
                *(short8*)((char*)wlds + bo) = wreg[q];
            }
            int ar = rt * 16 + ln;
            unsigned sw = ((unsigned)(ar & 7)) << 4;
            #pragma unroll
            for (int kc = 0; kc < 4; ++kc)
                af[kc] = *(short8*)((char*)actlds +
                          (((unsigned)(ar * 256 + (kc * 32 + g * 8) * 2)) ^ sw));
        }
        __syncthreads();                 // B2: wlds/act ready, af reads issued

        if (l < 7) {                     // prefetch W[l+1] into regs (lands during MFMA)
            #pragma unroll
            for (int q = 0; q < 4; ++q) {
                int idx = tid + q * 512;
                int wi = idx >> 4, wc = idx & 15;
                wreg[q] = *(const short8*)(p.W[l + 1] + wi * 128 + wc * 8);
            }
        }

        f32x4 acc[4];
        #pragma unroll
        for (int nt = 0; nt < 4; ++nt) {   // bias folded into C-init
            float bv = p.B[l][ch * 64 + nt * 16 + ln];
            acc[nt] = (f32x4){bv, bv, bv, bv};
        }
        #pragma unroll
        for (int kc = 0; kc < 4; ++kc) {
            #pragma unroll
            for (int nt = 0; nt < 4; ++nt) {
                int wi = ch * 64 + nt * 16 + ln;
                unsigned bo = (unsigned)(wi * 256 + kc * 64 + g * 16) ^ (unsigned)((wi & 7) << 4);
                short8 b = *(short8*)((char*)wlds + bo);
                acc[nt] = __builtin_amdgcn_mfma_f32_16x16x32_bf16(af[kc], b, acc[nt], 0, 0, 0);
            }
        }

        int mode = modes[l];
        #pragma unroll
        for (int nt = 0; nt < 4; ++nt) {
            int col = ch * 64 + nt * 16 + ln;
            #pragma unroll
            for (int r = 0; r < 4; ++r) {
                int lrow = rt * 16 + g * 4 + r;
                int row = rowBase + lrow;
                float v = silu_f(acc[nt][r]);
                if (mode == 1) { v += hreg[nt][r]; hreg[nt][r] = v; }
                else if (mode == 2) {
                    int cr = row > NEDGE - 1 ? NEDGE - 1 : row;
                    v += x[(size_t)cr * 128 + col];
                    hreg[nt][r] = v;
                } else if (mode == 3) {
                    if (row < NEDGE) out[(size_t)row * 128 + col] = v;
                }
                if (mode != 3) {
                    // pack adjacent cols via lane-pair exchange -> conflict-free b32 store
                    unsigned bits = (unsigned)(unsigned short)f2bf(v);
                    unsigned other = __shfl_xor((int)bits, 1, 64);
                    unsigned pk = (ln & 1) ? (other | (bits << 16)) : (bits | (other << 16));
                    if ((ln & 1) == (r & 1)) {
                        unsigned bo = ((unsigned)(lrow * 256 + (col & ~1) * 2))
                                      ^ (((unsigned)(lrow & 7)) << 4);
                        *(unsigned*)((char*)actlds + bo) = pk;
                    }
                }
            }
        }
    }
}

// ---------- launch ----------
extern "C" void kernel_launch(void* const* d_in, const int* in_sizes, int n_in,
                              void* d_out, int out_size, void* d_ws, size_t ws_size,
                              hipStream_t stream) {
    const float* x      = (const float*)d_in[0];
    const float* rbf    = (const float*)d_in[1];
    const float* sbf    = (const float*)d_in[2];
    const int*   idx_kj = (const int*)d_in[3];
    const int*   idx_ji = (const int*)d_in[4];
    const float* W_rbf  = (const float*)d_in[5];
    const float* W_sbf  = (const float*)d_in[6];
    const float* Wkj    = (const float*)d_in[7];
    const float* bkj    = (const float*)d_in[8];
    const float* Wji    = (const float*)d_in[9];
    const float* bji    = (const float*)d_in[10];
    const float* Wbil   = (const float*)d_in[11];
    const float* bW1    = (const float*)d_in[12];
    const float* bb1    = (const float*)d_in[13];
    const float* bW2    = (const float*)d_in[14];
    const float* bb2    = (const float*)d_in[15];
    const float* Wlin   = (const float*)d_in[16];
    const float* blin   = (const float*)d_in[17];
    const float* aW1    = (const float*)d_in[18];
    const float* ab1    = (const float*)d_in[19];
    const float* aW2    = (const float*)d_in[20];
    const float* ab2    = (const float*)d_in[21];
    const float* Wout   = (const float*)d_in[22];
    const float* bout   = (const float*)d_in[23];
    float* out = (float*)d_out;

    char* ws = (char*)d_ws;
    size_t off = 0;
    auto alloc = [&](size_t bytes) { char* p = ws + off; off += bytes; return p; };
    short* xb    = (short*)alloc((size_t)NEDGE * 128 * 2);
    short* xkj   = (short*)alloc((size_t)NEDGE * 128 * 2);
    short* hbb   = (short*)alloc((size_t)NEDGE * 128 * 2);
    float* sbfh  = (float*)alloc((size_t)NTRI * 8 * 4);
    float* sbfhp = (float*)alloc(((size_t)NTRI * 8 + 64) * 4);
    float* xji   = (float*)alloc((size_t)NEDGE * 128 * 4);
    float* h     = (float*)alloc((size_t)NEDGE * 128 * 4);
    short* WbT   = (short*)alloc((size_t)131072 * 2);
    short* Wt[10];
    for (int i = 0; i < 10; ++i) Wt[i] = (short*)alloc((size_t)16384 * 2);
    int* counts  = (int*)alloc((size_t)NEDGE * 4);
    int* partial = (int*)alloc((size_t)NEDGE * 4);
    int* rowptr  = (int*)alloc((size_t)NEDGE * 4);
    int* wcur    = (int*)alloc((size_t)NEDGE * 4);
    int* bsum    = (int*)alloc(256 * 4);
    int* kjp     = (int*)alloc((size_t)(NTRI + 64) * 4);
    (void)ws_size; (void)n_in; (void)in_sizes; (void)out_size;

    hipMemsetAsync(counts, 0, (size_t)NEDGE * 4, stream);

    cvt_kernel<<<dim3((NEDGE * 128 / 4 + 255) / 256), 256, 0, stream>>>(x, xb, NEDGE * 128 / 4);
    cvt_kernel<<<dim3((131072 / 4 + 255) / 256), 256, 0, stream>>>(Wbil, WbT, 131072 / 4);

    TP tp;
    const float* srcs[10] = {Wkj, Wji, bW1, bW2, Wlin, aW1, aW1 + 16384, aW2, aW2 + 16384, Wout};
    for (int i = 0; i < 10; ++i) { tp.s[i] = srcs[i]; tp.d[i] = Wt[i]; }
    t128_all<<<dim3(64, 10), 256, 0, stream>>>(tp);

    sbfh_kernel<<<dim3(NTRI / 32), 256, 0, stream>>>(sbf, W_sbf, sbfh);

    // CSR of idx_ji
    int NB1 = (NEDGE + 255) / 256;   // 196
    hist_kernel<<<dim3((NTRI + 255) / 256), 256, 0, stream>>>(idx_ji, counts);
    scan1_kernel<<<dim3(NB1), 256, 0, stream>>>(counts, partial, bsum);
    scan2_kernel<<<dim3(1), 256, 0, stream>>>(bsum, NB1);
    scan3_kernel<<<dim3(NB1), 256, 0, stream>>>(partial, bsum, rowptr, wcur);
    scatter_kernel<<<dim3((NTRI + 255) / 256), 256, 0, stream>>>(idx_ji, idx_kj, sbfh,
                                                                 wcur, kjp, sbfhp);

    int gE = (NEDGE + 63) / 64;   // 782
    // x_ji = silu(x@Wji+bji) f32 ; x_kj = silu(x@Wkj+bkj)*(rbf@W_rbf) bf16
    gemm_x<<<gE, 256, 0, stream>>>(xb, Wt[1], Wt[0], bji, bkj, rbf, W_rbf, xji, xkj);

    // fused bilinear + segment-sum: h = xji + (y @ Wbil), hb = bf16(h)
    bilinear_fused<<<dim3((NEDGE + BE - 1) / BE), 512, 0, stream>>>(
        xkj, sbfhp, kjp, rowptr, counts, xji, WbT, h, hbb);

    // fused 8-layer residual chain -> out
    ChainP cp;
    cp.W[0] = Wt[2]; cp.B[0] = bb1;
    cp.W[1] = Wt[3]; cp.B[1] = bb2;
    cp.W[2] = Wt[4]; cp.B[2] = blin;
    cp.W[3] = Wt[5]; cp.B[3] = ab1;
    cp.W[4] = Wt[7]; cp.B[4] = ab2;
    cp.W[5] = Wt[6]; cp.B[5] = ab1 + 128;
    cp.W[6] = Wt[8]; cp.B[6] = ab2 + 128;
    cp.W[7] = Wt[9]; cp.B[7] = bout;
    chain_kernel<<<gE, 512, 0, stream>>>(cp, hbb, h, x, out);
}